// Round 1
// baseline (57228.900 us; speedup 1.0000x reference)
//
#include <hip/hip_runtime.h>
#include <hip/hip_cooperative_groups.h>

namespace cg = cooperative_groups;

#define TT 500
#define BB 128
#define HH 400
#define AAc 64
#define UUc 50
#define OD  121

// smem layout in floats:
// bufA: [0, 4352)         2 x 32 x 68   (k-chunk double buffer, part A)
// bufB: [4352, 8704)      2 x 32 x 68   (part B)
// G:    [8704, 12400)     56 x 66       (gate pre-activations / p / O)
#define SM_BUFA 0
#define SM_BUFB 4352
#define SM_G    8704
#define SM_TOT  12400

struct Seg { const float* p; int len; int relu; };

struct Params {
  const float* seq; const int* cid;
  const float *Wi1, *Wh1, *bi1, *bh1;
  const float *Wc,  *bc;
  const float *Wi2, *Wh2, *bi2, *bh2;
  const float *Wi3, *Wh3, *bi3, *bh3;
  const float *Wl,  *bl;
  float* out;
  float *h1r, *h2r, *h3r, *wr, *kap;
};

__device__ __forceinline__ float4 relu4(float4 v) {
  v.x = fmaxf(v.x, 0.f); v.y = fmaxf(v.y, 0.f);
  v.z = fmaxf(v.z, 0.f); v.w = fmaxf(v.w, 0.f);
  return v;
}

template<int MAXR>
__device__ __forceinline__ void gemm_chunk(const float* const* wp, const float* buf,
                                           int lane, int k0, int vk, float* acc)
{
  // vk is always a multiple of 8 here (K in {400,464,1264}, chunk=32, tails=16)
  for (int k8 = 0; k8 < vk; k8 += 8) {
    float w[MAXR][8];
#pragma unroll
    for (int r = 0; r < MAXR; ++r) {
      const float* q = wp[r] + k0 + k8;
      float4 a = *(const float4*)q;
      float4 b = *(const float4*)(q + 4);
      w[r][0]=a.x; w[r][1]=a.y; w[r][2]=a.z; w[r][3]=a.w;
      w[r][4]=b.x; w[r][5]=b.y; w[r][6]=b.z; w[r][7]=b.w;
    }
#pragma unroll
    for (int kk = 0; kk < 8; ++kk) {
      float x = buf[(k8 + kk)*68 + lane];
#pragma unroll
      for (int r = 0; r < MAXR; ++r) acc[r] = fmaf(x, w[r][kk], acc[r]);
    }
  }
}

// Generic two-part GEMM: waves [0,partWaves) accumulate part A (input x W_ih),
// waves [partWaves,8) part B (h_prev x W_hh). Results land in shared G:
// part A rows at G[l], part B rows at G[bofsG + l].
// Row mapping: gateMap ? (gate*400 + rr0 + l%R) : (rr0 + l).
template<int MAXR>
__device__ void run_gemm(const Seg* segA, int nsegA, int KA,
                         Seg segB, int KB,
                         const float* WA, int ldA, const float* WB, int ldB,
                         int rows, int R, int gateMap, int rr0,
                         int partWaves, int bh, int tid, float* smem, int bofsG)
{
  float* bufA = smem + SM_BUFA;
  float* bufB = smem + SM_BUFB;
  float* G    = smem + SM_G;
  const int lane = tid & 63;
  const int wave = tid >> 6;

  const int part = (wave < partWaves) ? 0 : 1;
  const int ng   = part ? (8 - partWaves) : partWaves;   // own-part group count (>0 on taken path)
  const int rg   = part ? (wave - partWaves) : wave;
  const int per  = (rows + ng - 1) / ng;
  const int l0   = rg * per;
  int myn = rows - l0; if (myn < 0) myn = 0; if (myn > per) myn = per;

  const float* Wp = part ? WB : WA;
  const int ld    = part ? ldB : ldA;
  const int K     = part ? KB : KA;

  const float* wp[MAXR];
#pragma unroll
  for (int r = 0; r < MAXR; ++r) {
    int l = l0 + r; if (l >= rows) l = rows - 1; if (l < 0) l = 0;
    int wrow;
    if (gateMap) { int gate = l / R; int rr = l - gate*R; wrow = gate*HH + rr0 + rr; }
    else         { wrow = rr0 + l; }
    wp[r] = Wp + (size_t)wrow * ld;
  }
  float acc[MAXR];
#pragma unroll
  for (int r = 0; r < MAXR; ++r) acc[r] = 0.f;

  const int NCA  = (KA + 31) >> 5;
  const int NCB  = (KB + 31) >> 5;
  const int NC   = NCA > NCB ? NCA : NCB;
  const int NCme = part ? NCB : NCA;

  // staging role: threads 0..255 stage part A chunks, 256..511 stage part B
  const int su = tid & 255;
  const int sk = su >> 3;          // 0..31 (k within chunk)
  const int sb = (su & 7) * 8;     // 0..56 (b-octet)
  const int sPart = (tid < 256) ? 0 : 1;
  const Seg* ssegs; int snseg, sK;
  if (sPart == 0) { ssegs = segA;  snseg = nsegA; sK = KA; }
  else            { ssegs = &segB; snseg = 1;     sK = KB; }

  float4 h0, h1v;
  for (int c = 0; c < NC; ++c) {
    // load chunk c for my staging part into registers
    bool doStage = false;
    int kg = c*32 + sk;
    if (sK > 0 && kg < sK) {
      doStage = true;
      int kk = kg; int si = 0;
      while (si < snseg - 1 && kk >= ssegs[si].len) { kk -= ssegs[si].len; ++si; }
      const float* sp = ssegs[si].p + (size_t)kk * BB + bh*64 + sb;
      h0  = *(const float4*)sp;
      h1v = *(const float4*)(sp + 4);
      if (ssegs[si].relu) { h0 = relu4(h0); h1v = relu4(h1v); }
    }
    // compute chunk c-1 (overlaps the global loads above)
    if (c > 0) {
      int cp = c - 1;
      if (cp < NCme) {
        int k0 = cp*32; int vk = K - k0; if (vk > 32) vk = 32;
        const float* buf = (part ? bufB : bufA) + (cp & 1)*(32*68);
        gemm_chunk<MAXR>(wp, buf, lane, k0, vk, acc);
      }
    }
    // commit staged chunk
    if (doStage) {
      float* db = (sPart ? bufB : bufA) + (c & 1)*(32*68) + sk*68 + sb;
      *(float4*)db       = h0;
      *(float4*)(db + 4) = h1v;
    }
    __syncthreads();
  }
  { // final chunk
    int cp = NC - 1;
    if (cp >= 0 && cp < NCme) {
      int k0 = cp*32; int vk = K - k0; if (vk > 32) vk = 32;
      const float* buf = (part ? bufB : bufA) + (cp & 1)*(32*68);
      gemm_chunk<MAXR>(wp, buf, lane, k0, vk, acc);
    }
  }
  const int ofs = part ? bofsG : 0;
#pragma unroll
  for (int r = 0; r < MAXR; ++r) {
    if (r < myn) G[(ofs + l0 + r)*66 + lane] = acc[r];
  }
  __syncthreads();
}

__device__ void gru_combine(const Params& p, int g, int t, int bh, int rr0, int R,
                            const float* G, int Bofs,
                            const float* bih, const float* bhh,
                            const float* hprev, float* hnew, int tid)
{
  const int b  = tid & 63;
  const int bg = bh*64 + b;
  for (int rr = tid >> 6; rr < R; rr += 8) {
    const int row = rr0 + rr;
    float gaR, gaZ, gaN;
    if (g == 1) {
      // gi1 = x_t @ W_ih1[:, :3].T  (cols 3..66 multiply zeros)
      const float x0 = p.seq[((size_t)t*BB + bg)*3 + 0];
      const float x1 = p.seq[((size_t)t*BB + bg)*3 + 1];
      const float x2 = p.seq[((size_t)t*BB + bg)*3 + 2];
      const float* w0 = p.Wi1 + (size_t)(0*HH + row)*67;
      const float* w1 = p.Wi1 + (size_t)(1*HH + row)*67;
      const float* w2 = p.Wi1 + (size_t)(2*HH + row)*67;
      gaR = x0*w0[0] + x1*w0[1] + x2*w0[2];
      gaZ = x0*w1[0] + x1*w1[1] + x2*w1[2];
      gaN = x0*w2[0] + x1*w2[1] + x2*w2[2];
    } else {
      gaR = G[(0*R + rr)*66 + b];
      gaZ = G[(1*R + rr)*66 + b];
      gaN = G[(2*R + rr)*66 + b];
    }
    const float gbR = G[(Bofs + 0*R + rr)*66 + b];
    const float gbZ = G[(Bofs + 1*R + rr)*66 + b];
    const float gbN = G[(Bofs + 2*R + rr)*66 + b];
    const float ir  = gaR + bih[row],        hr = gbR + bhh[row];
    const float iz  = gaZ + bih[HH + row],   hz = gbZ + bhh[HH + row];
    const float inn = gaN + bih[2*HH + row], hn = gbN + bhh[2*HH + row];
    const float rgate = 1.f / (1.f + expf(-(ir + hr)));
    const float zgate = 1.f / (1.f + expf(-(iz + hz)));
    const float ngate = tanhf(inn + rgate*hn);
    const float hp = hprev[(size_t)row*BB + bg];
    hnew[(size_t)row*BB + bg] = (1.f - zgate)*ngate + zgate*hp;
  }
}

__device__ void attn_post(const Params& p, int t, int bh, float* smem, int tid)
{
  float* G  = smem + SM_G;     // p (pre-bias), 30 rows
  float* AL = smem + SM_BUFB;  // [30][66]: alpha(0..9), beta(10..19), new kappa(20..29)
  float* PH = smem + SM_G;     // [50][66], overlays G (G dead after phase1)
  float* WR = smem + SM_BUFA;  // [64][66]
  const int b  = tid & 63;
  const int bg = bh*64 + b;

  // phase1: exponentials + kappa accumulation (fp32, matches reference)
  for (int l = tid >> 6; l < 30; l += 8) {
    float v = expf(G[l*66 + b] + p.bc[l]);
    if (l >= 20) {
      const int j = l - 20;
      float kk = p.kap[(size_t)bg*10 + j] + v;
      p.kap[(size_t)bg*10 + j] = kk;
      v = kk;
    }
    AL[l*66 + b] = v;
  }
  __syncthreads();
  // phase2: phi[b][u]
  for (int u = tid >> 6; u < UUc; u += 8) {
    float ph = 0.f;
#pragma unroll
    for (int j = 0; j < 10; ++j) {
      const float al = AL[j*66 + b];
      const float be = AL[(10 + j)*66 + b];
      const float ka = AL[(20 + j)*66 + b];
      const float d  = ka - (float)u;
      ph += al * expf(-be * d * d);
    }
    PH[u*66 + b] = ph;
  }
  __syncthreads();
  // phase3: w[b][a] = sum_{u: char==a} phi[b][u]
  for (int i = tid; i < 64*66; i += 512) WR[i] = 0.f;
  __syncthreads();
  if (tid < 64) {
    for (int u = 0; u < UUc; ++u) {
      const int a = p.cid[(size_t)bg*UUc + u] & 63;
      WR[a*66 + b] += PH[u*66 + b];
    }
  }
  __syncthreads();
  float* wring = p.wr + (size_t)(t & 7)*AAc*BB;
  for (int i = tid; i < AAc*64; i += 512) {
    const int a = i >> 6, bb2 = i & 63;
    wring[(size_t)a*BB + bh*64 + bb2] = WR[a*66 + bb2];
  }
}

__device__ void out_store(const Params& p, int t, int bh, int j0, int nj,
                          const float* G, int tid)
{
  for (int idx = tid; idx < 64*16; idx += 512) {
    const int b = idx >> 4, jl = idx & 15;
    if (jl < nj) {
      const float v = G[jl*66 + b] + p.bl[j0 + jl];
      const int bg = bh*64 + b;
      p.out[((size_t)bg*TT + t)*OD + j0 + jl] = v;
    }
  }
}

__global__ __launch_bounds__(512, 2) void hwnet_kernel(Params p)
{
  __shared__ float smem[SM_TOT];
  cg::grid_group grid = cg::this_grid();
  const int wg  = blockIdx.x;
  const int tid = threadIdx.x;

  // init: zero the t=-1 ring slots (slot 7) and kappa
  {
    const size_t n1 = (size_t)HH*BB;            // 51200
    const size_t tot = 3*n1 + (size_t)BB*10;
    for (size_t i = (size_t)wg*512 + tid; i < tot; i += (size_t)256*512) {
      if      (i <   n1) p.h1r[7*n1 + i]        = 0.f;
      else if (i < 2*n1) p.h2r[7*n1 + (i - n1)] = 0.f;
      else if (i < 3*n1) p.h3r[7*n1 + (i - 2*n1)] = 0.f;
      else               p.kap[i - 3*n1]        = 0.f;
    }
  }
  grid.sync();

  for (int s = 0; s < TT + 4; ++s) {
    if (wg < 92) {                                    // GRU2, t = s-2
      const int t = s - 2;
      if (t >= 0 && t < TT) {
        const int idx = wg, tile = idx >> 1, bh = idx & 1;
        const int rr0 = (tile*HH)/46, R = ((tile + 1)*HH)/46 - rr0;
        Seg segA[2] = { { p.h1r + (size_t)(t & 7)*HH*BB, HH, 1 },
                        { p.wr  + (size_t)(t & 7)*AAc*BB, AAc, 1 } };
        Seg segB    = { p.h2r + (size_t)((t - 1) & 7)*HH*BB, HH, 0 };
        run_gemm<7>(segA, 2, 464, segB, 400, p.Wi2, 464, p.Wh2, 400,
                    3*R, R, 1, rr0, 4, bh, tid, smem, 28);
        gru_combine(p, 2, t, bh, rr0, R, smem + SM_G, 28, p.bi2, p.bh2,
                    p.h2r + (size_t)((t - 1) & 7)*HH*BB,
                    p.h2r + (size_t)(t & 7)*HH*BB, tid);
      }
    } else if (wg < 184) {                            // GRU3, t = s-3
      const int t = s - 3;
      if (t >= 0 && t < TT) {
        const int idx = wg - 92, tile = idx >> 1, bh = idx & 1;
        const int rr0 = (tile*HH)/46, R = ((tile + 1)*HH)/46 - rr0;
        Seg segA[2] = { { p.h2r + (size_t)(t & 7)*HH*BB, HH, 1 },
                        { p.wr  + (size_t)(t & 7)*AAc*BB, AAc, 1 } };
        Seg segB    = { p.h3r + (size_t)((t - 1) & 7)*HH*BB, HH, 0 };
        run_gemm<7>(segA, 2, 464, segB, 400, p.Wi3, 464, p.Wh3, 400,
                    3*R, R, 1, rr0, 4, bh, tid, smem, 28);
        gru_combine(p, 3, t, bh, rr0, R, smem + SM_G, 28, p.bi3, p.bh3,
                    p.h3r + (size_t)((t - 1) & 7)*HH*BB,
                    p.h3r + (size_t)(t & 7)*HH*BB, tid);
      }
    } else if (wg < 230) {                            // GRU1, t = s
      const int t = s;
      if (t < TT) {
        const int idx = wg - 184, tile = idx >> 1, bh = idx & 1;
        const int rr0 = (tile*HH)/23, R = ((tile + 1)*HH)/23 - rr0;
        Seg segA[1] = { { p.h1r, 0, 0 } };            // unused (KA=0)
        Seg segB    = { p.h1r + (size_t)((t - 1) & 7)*HH*BB, HH, 0 };
        run_gemm<7>(segA, 1, 0, segB, 400, p.Wi1, 67, p.Wh1, 400,
                    3*R, R, 1, rr0, 0, bh, tid, smem, 0);
        gru_combine(p, 1, t, bh, rr0, R, smem + SM_G, 0, p.bi1, p.bh1,
                    p.h1r + (size_t)((t - 1) & 7)*HH*BB,
                    p.h1r + (size_t)(t & 7)*HH*BB, tid);
      }
    } else if (wg < 246) {                            // OUT, t = s-4
      const int t = s - 4;
      if (t >= 0 && t < TT) {
        const int idx = wg - 230, jt = idx >> 1, bh = idx & 1;
        const int j0 = (jt*OD)/8, nj = ((jt + 1)*OD)/8 - j0;
        Seg segA[4] = { { p.h3r + (size_t)(t & 7)*HH*BB, HH, 1 },
                        { p.h2r + (size_t)(t & 7)*HH*BB, HH, 1 },
                        { p.h1r + (size_t)(t & 7)*HH*BB, HH, 1 },
                        { p.wr  + (size_t)(t & 7)*AAc*BB, AAc, 1 } };
        Seg segB    = { nullptr, 0, 0 };
        run_gemm<2>(segA, 4, 1264, segB, 0, p.Wl, 1264, nullptr, 0,
                    nj, 1 /*unused*/, 0, j0, 8, bh, tid, smem, 28);
        out_store(p, t, bh, j0, nj, smem + SM_G, tid);
      }
    } else if (wg < 248) {                            // ATTN, t = s-1
      const int t = s - 1;
      if (t >= 0 && t < TT) {
        const int bh = wg - 246;
        Seg segA[1] = { { p.h1r + (size_t)(t & 7)*HH*BB, HH, 0 } };
        Seg segB    = { nullptr, 0, 0 };
        run_gemm<4>(segA, 1, 400, segB, 0, p.Wc, 400, nullptr, 0,
                    30, 1 /*unused*/, 0, 0, 8, bh, tid, smem, 28);
        attn_post(p, t, bh, smem, tid);
      }
    }
    // wgs 248..255 idle compute; everyone syncs
    grid.sync();
  }
}

extern "C" void kernel_launch(void* const* d_in, const int* in_sizes, int n_in,
                              void* d_out, int out_size, void* d_ws, size_t ws_size,
                              hipStream_t stream)
{
  (void)in_sizes; (void)n_in; (void)out_size; (void)ws_size;
  Params p;
  p.seq = (const float*)d_in[0];
  p.cid = (const int*)  d_in[1];
  p.Wi1 = (const float*)d_in[2];  p.Wh1 = (const float*)d_in[3];
  p.bi1 = (const float*)d_in[4];  p.bh1 = (const float*)d_in[5];
  p.Wc  = (const float*)d_in[6];  p.bc  = (const float*)d_in[7];
  p.Wi2 = (const float*)d_in[8];  p.Wh2 = (const float*)d_in[9];
  p.bi2 = (const float*)d_in[10]; p.bh2 = (const float*)d_in[11];
  p.Wi3 = (const float*)d_in[12]; p.Wh3 = (const float*)d_in[13];
  p.bi3 = (const float*)d_in[14]; p.bh3 = (const float*)d_in[15];
  p.Wl  = (const float*)d_in[16]; p.bl  = (const float*)d_in[17];
  p.out = (float*)d_out;

  float* ws = (float*)d_ws;
  p.h1r = ws; ws += (size_t)8*HH*BB;
  p.h2r = ws; ws += (size_t)8*HH*BB;
  p.h3r = ws; ws += (size_t)8*HH*BB;
  p.wr  = ws; ws += (size_t)8*AAc*BB;
  p.kap = ws; ws += (size_t)BB*10;

  void* args[] = { &p };
  hipLaunchCooperativeKernel(reinterpret_cast<void*>(hwnet_kernel),
                             dim3(256), dim3(512), args, 0, stream);
}

// Round 2
// 29741.342 us; speedup vs baseline: 1.9242x; 1.9242x over previous
//
#include <hip/hip_runtime.h>

#define TT 500
#define BB 128
#define HH 400
#define AAc 64
#define UUc 50
#define OD  121

// dynamic LDS layout in floats:
// bufA: [0, 4352)          2 x 32 x 68   (k-chunk double buffer, part A)
// bufB: [4352, 8704)       2 x 32 x 68   (part B)
// G:    [8704, 12400)      56 x 66       (gate pre-activations / p / O)
// W:    [12400, 36240)     per-WG weight cache (loaded once, read every step)
#define SM_BUFA 0
#define SM_BUFB 4352
#define SM_G    8704
#define SM_W    12400
#define SM_WSZ  23840
#define SM_TOT  (SM_W + SM_WSZ)          // 36240 floats = 144960 bytes
#define CID_OFS  (SM_W + 12032)          // attn: 64*50 ints
#define KAP_OFS  (SM_W + 15360)          // attn: 10*64 floats (persistent kappa)
#define WI1C_OFS (SM_W + 21760)          // gru1: 3R*3 floats (Wi1 first 3 cols)

struct Seg { const float* p; int len; int relu; };

struct Params {
  const float* seq; const int* cid;
  const float *Wi1, *Wh1, *bi1, *bh1;
  const float *Wc,  *bc;
  const float *Wi2, *Wh2, *bi2, *bh2;
  const float *Wi3, *Wh3, *bi3, *bh3;
  const float *Wl,  *bl;
  float* out;
  unsigned* bar;
  float *h1r, *h2r, *h3r, *wr;
};

__device__ __forceinline__ float4 relu4(float4 v) {
  v.x = fmaxf(v.x, 0.f); v.y = fmaxf(v.y, 0.f);
  v.z = fmaxf(v.z, 0.f); v.w = fmaxf(v.w, 0.f);
  return v;
}

// Grid barrier: monotonic counter in device memory (zeroed via hipMemsetAsync
// before launch). Release = __threadfence (L2 writeback) before arrival;
// acquire = __threadfence (L1/L2 inv) after the spin. Co-residency guaranteed
// by hipLaunchCooperativeKernel.
__device__ __forceinline__ void gbar(unsigned* cnt, unsigned target, int tid) {
  __syncthreads();
  if (tid == 0) {
    __threadfence();
    __hip_atomic_fetch_add(cnt, 1u, __ATOMIC_RELAXED, __HIP_MEMORY_SCOPE_AGENT);
    while (__hip_atomic_load(cnt, __ATOMIC_RELAXED, __HIP_MEMORY_SCOPE_AGENT) < target)
      __builtin_amdgcn_s_sleep(1);
    __threadfence();
  }
  __syncthreads();
}

// Copy `rows` weight rows (mapped through gateMap) of width Kc into LDS,
// row-major contiguous. Called once per kernel, before the time loop.
__device__ void preW(float* dst, const float* W, int ld, int Kc, int rows,
                     int gateMap, int rr0, int R, int tid)
{
  const int q = Kc >> 2;
  const int tot = rows * q;
  for (int i = tid; i < tot; i += 512) {
    int l = i / q, kq = (i - l * q) << 2;
    int wrow = gateMap ? ((l / R) * HH + rr0 + (l % R)) : (rr0 + l);
    *(float4*)(dst + (size_t)l * Kc + kq) = *(const float4*)(W + (size_t)wrow * ld + kq);
  }
}

template<int MAXR>
__device__ __forceinline__ void gemm_chunk(const float* const* wp, const float* buf,
                                           int lane, int k0, int vk, float* acc)
{
  for (int k8 = 0; k8 < vk; k8 += 8) {
    float w[MAXR][8];
#pragma unroll
    for (int r = 0; r < MAXR; ++r) {
      const float* q = wp[r] + k0 + k8;          // LDS, wave-uniform -> broadcast
      float4 a = *(const float4*)q;
      float4 b = *(const float4*)(q + 4);
      w[r][0]=a.x; w[r][1]=a.y; w[r][2]=a.z; w[r][3]=a.w;
      w[r][4]=b.x; w[r][5]=b.y; w[r][6]=b.z; w[r][7]=b.w;
    }
#pragma unroll
    for (int kk = 0; kk < 8; ++kk) {
      float x = buf[(k8 + kk)*68 + lane];
#pragma unroll
      for (int r = 0; r < MAXR; ++r) acc[r] = fmaf(x, w[r][kk], acc[r]);
    }
  }
}

// Two-part GEMM; weights come from LDS (wAlds/wBlds, row-major, mapping already
// applied at preload). x panels staged global->LDS double-buffered as before.
template<int MAXR>
__device__ void run_gemm(const Seg* segA, int nsegA, int KA,
                         Seg segB, int KB,
                         const float* wAlds, const float* wBlds,
                         int rows, int partWaves, int bh, int tid,
                         float* smem, int bofsG)
{
  float* bufA = smem + SM_BUFA;
  float* bufB = smem + SM_BUFB;
  float* G    = smem + SM_G;
  const int lane = tid & 63;
  const int wave = tid >> 6;

  const int part = (wave < partWaves) ? 0 : 1;
  const int ng   = part ? (8 - partWaves) : partWaves;
  const int rg   = part ? (wave - partWaves) : wave;
  const int per  = (rows + ng - 1) / ng;
  const int l0   = rg * per;
  int myn = rows - l0; if (myn < 0) myn = 0; if (myn > per) myn = per;

  const float* Wb = part ? wBlds : wAlds;
  const int Kc    = part ? KB : KA;
  const int K     = Kc;

  const float* wp[MAXR];
#pragma unroll
  for (int r = 0; r < MAXR; ++r) wp[r] = Wb + (size_t)(l0 + r) * Kc;  // OOB rows read in-allocation garbage; guarded at G-write

  float acc[MAXR];
#pragma unroll
  for (int r = 0; r < MAXR; ++r) acc[r] = 0.f;

  const int NCA  = (KA + 31) >> 5;
  const int NCB  = (KB + 31) >> 5;
  const int NC   = NCA > NCB ? NCA : NCB;
  const int NCme = part ? NCB : NCA;

  const int su = tid & 255;
  const int sk = su >> 3;
  const int sb = (su & 7) * 8;
  const int sPart = (tid < 256) ? 0 : 1;
  const Seg* ssegs; int snseg, sK;
  if (sPart == 0) { ssegs = segA;  snseg = nsegA; sK = KA; }
  else            { ssegs = &segB; snseg = 1;     sK = KB; }

  float4 h0, h1v;
  for (int c = 0; c < NC; ++c) {
    bool doStage = false;
    int kg = c*32 + sk;
    if (sK > 0 && kg < sK) {
      doStage = true;
      int kk = kg; int si = 0;
      while (si < snseg - 1 && kk >= ssegs[si].len) { kk -= ssegs[si].len; ++si; }
      const float* sp = ssegs[si].p + (size_t)kk * BB + bh*64 + sb;
      h0  = *(const float4*)sp;
      h1v = *(const float4*)(sp + 4);
      if (ssegs[si].relu) { h0 = relu4(h0); h1v = relu4(h1v); }
    }
    if (c > 0) {
      int cp = c - 1;
      if (cp < NCme) {
        int k0 = cp*32; int vk = K - k0; if (vk > 32) vk = 32;
        const float* buf = (part ? bufB : bufA) + (cp & 1)*(32*68);
        gemm_chunk<MAXR>(wp, buf, lane, k0, vk, acc);
      }
    }
    if (doStage) {
      float* db = (sPart ? bufB : bufA) + (c & 1)*(32*68) + sk*68 + sb;
      *(float4*)db       = h0;
      *(float4*)(db + 4) = h1v;
    }
    __syncthreads();
  }
  {
    int cp = NC - 1;
    if (cp >= 0 && cp < NCme) {
      int k0 = cp*32; int vk = K - k0; if (vk > 32) vk = 32;
      const float* buf = (part ? bufB : bufA) + (cp & 1)*(32*68);
      gemm_chunk<MAXR>(wp, buf, lane, k0, vk, acc);
    }
  }
  const int ofs = part ? bofsG : 0;
#pragma unroll
  for (int r = 0; r < MAXR; ++r) {
    if (r < myn) G[(ofs + l0 + r)*66 + lane] = acc[r];
  }
  __syncthreads();
}

__device__ void gru_combine(const Params& p, int g, int t, int bh, int rr0, int R,
                            const float* G, int Bofs,
                            const float* bih, const float* bhh,
                            const float* hprev, float* hnew,
                            const float* wi1c, int tid)
{
  const int b  = tid & 63;
  const int bg = bh*64 + b;
  float x0 = 0.f, x1 = 0.f, x2 = 0.f;
  if (g == 1) {
    x0 = p.seq[((size_t)t*BB + bg)*3 + 0];
    x1 = p.seq[((size_t)t*BB + bg)*3 + 1];
    x2 = p.seq[((size_t)t*BB + bg)*3 + 2];
  }
  for (int rr = tid >> 6; rr < R; rr += 8) {
    const int row = rr0 + rr;
    float gaR, gaZ, gaN;
    if (g == 1) {
      const float* w0 = wi1c + (0*R + rr)*3;
      const float* w1 = wi1c + (1*R + rr)*3;
      const float* w2 = wi1c + (2*R + rr)*3;
      gaR = x0*w0[0] + x1*w0[1] + x2*w0[2];
      gaZ = x0*w1[0] + x1*w1[1] + x2*w1[2];
      gaN = x0*w2[0] + x1*w2[1] + x2*w2[2];
    } else {
      gaR = G[(0*R + rr)*66 + b];
      gaZ = G[(1*R + rr)*66 + b];
      gaN = G[(2*R + rr)*66 + b];
    }
    const float gbR = G[(Bofs + 0*R + rr)*66 + b];
    const float gbZ = G[(Bofs + 1*R + rr)*66 + b];
    const float gbN = G[(Bofs + 2*R + rr)*66 + b];
    const float ir  = gaR + bih[row],        hr = gbR + bhh[row];
    const float iz  = gaZ + bih[HH + row],   hz = gbZ + bhh[HH + row];
    const float inn = gaN + bih[2*HH + row], hn = gbN + bhh[2*HH + row];
    const float rgate = 1.f / (1.f + expf(-(ir + hr)));
    const float zgate = 1.f / (1.f + expf(-(iz + hz)));
    const float ngate = tanhf(inn + rgate*hn);
    const float hp = hprev[(size_t)row*BB + bg];
    hnew[(size_t)row*BB + bg] = (1.f - zgate)*ngate + zgate*hp;
  }
}

__device__ void attn_post(const Params& p, int t, int bh, float* smem, int tid)
{
  float* G    = smem + SM_G;
  float* AL   = smem + SM_BUFB;
  float* PH   = smem + SM_G;       // overlays G (dead after phase1)
  float* WR   = smem + SM_BUFA;
  int*   cidl = (int*)(smem + CID_OFS);
  float* kapl = smem + KAP_OFS;
  const int b = tid & 63;

  for (int l = tid >> 6; l < 30; l += 8) {
    float v = expf(G[l*66 + b] + p.bc[l]);
    if (l >= 20) {
      const int j = l - 20;
      float kk = kapl[j*64 + b] + v;
      kapl[j*64 + b] = kk;
      v = kk;
    }
    AL[l*66 + b] = v;
  }
  __syncthreads();
  for (int u = tid >> 6; u < UUc; u += 8) {
    float ph = 0.f;
#pragma unroll
    for (int j = 0; j < 10; ++j) {
      const float al = AL[j*66 + b];
      const float be = AL[(10 + j)*66 + b];
      const float ka = AL[(20 + j)*66 + b];
      const float d  = ka - (float)u;
      ph += al * expf(-be * d * d);
    }
    PH[u*66 + b] = ph;
  }
  __syncthreads();
  for (int i = tid; i < 64*66; i += 512) WR[i] = 0.f;
  __syncthreads();
  if (tid < 64) {
    for (int u = 0; u < UUc; ++u) {
      const int a = cidl[b*UUc + u];
      WR[a*66 + b] += PH[u*66 + b];
    }
  }
  __syncthreads();
  float* wring = p.wr + (size_t)(t & 7)*AAc*BB;
  for (int i = tid; i < AAc*64; i += 512) {
    const int a = i >> 6, bb2 = i & 63;
    wring[(size_t)a*BB + bh*64 + bb2] = WR[a*66 + bb2];
  }
}

__device__ void out_store(const Params& p, int t, int bh, int j0, int nj,
                          const float* G, int tid)
{
  for (int idx = tid; idx < 64*16; idx += 512) {
    const int b = idx >> 4, jl = idx & 15;
    if (jl < nj) {
      const float v = G[jl*66 + b] + p.bl[j0 + jl];
      const int bg = bh*64 + b;
      p.out[((size_t)bg*TT + t)*OD + j0 + jl] = v;
    }
  }
}

__global__ __launch_bounds__(512) void hwnet_kernel(Params p)
{
  extern __shared__ float smem[];
  const int wg  = blockIdx.x;
  const int tid = threadIdx.x;
  unsigned* cnt = p.bar;
  float* wA = smem + SM_W;

  // zero the t=-1 ring slots (slot 7)
  {
    const size_t n1 = (size_t)HH*BB;
    for (size_t i = (size_t)wg*512 + tid; i < 3*n1; i += (size_t)256*512) {
      if      (i <   n1) p.h1r[7*n1 + i]          = 0.f;
      else if (i < 2*n1) p.h2r[7*n1 + (i - n1)]   = 0.f;
      else               p.h3r[7*n1 + (i - 2*n1)] = 0.f;
    }
  }

  // role setup + one-time weight preload into LDS
  int stage = 5, bh = 0, rr0 = 0, R = 1, rows = 0, j0 = 0;
  if (wg < 92) {                                    // GRU2
    stage = 0; const int idx = wg, tile = idx >> 1; bh = idx & 1;
    rr0 = (tile*HH)/46; R = ((tile + 1)*HH)/46 - rr0; rows = 3*R;
    preW(wA, p.Wi2, 464, 464, rows, 1, rr0, R, tid);
    preW(wA + (size_t)rows*464, p.Wh2, 400, 400, rows, 1, rr0, R, tid);
  } else if (wg < 184) {                            // GRU3
    stage = 1; const int idx = wg - 92, tile = idx >> 1; bh = idx & 1;
    rr0 = (tile*HH)/46; R = ((tile + 1)*HH)/46 - rr0; rows = 3*R;
    preW(wA, p.Wi3, 464, 464, rows, 1, rr0, R, tid);
    preW(wA + (size_t)rows*464, p.Wh3, 400, 400, rows, 1, rr0, R, tid);
  } else if (wg < 230) {                            // GRU1
    stage = 2; const int idx = wg - 184, tile = idx >> 1; bh = idx & 1;
    rr0 = (tile*HH)/23; R = ((tile + 1)*HH)/23 - rr0; rows = 3*R;
    preW(wA, p.Wh1, 400, 400, rows, 1, rr0, R, tid);
    for (int i = tid; i < rows*3; i += 512) {
      const int l = i/3, c = i - 3*l;
      const int wrow = (l / R)*HH + rr0 + (l % R);
      smem[WI1C_OFS + i] = p.Wi1[(size_t)wrow*67 + c];
    }
  } else if (wg < 246) {                            // OUT
    stage = 3; const int idx = wg - 230, jt = idx >> 1; bh = idx & 1;
    j0 = (jt*OD)/8; rows = ((jt + 1)*OD)/8 - j0;
    preW(wA, p.Wl, 1264, 1264, rows, 0, j0, 1, tid);
  } else if (wg < 248) {                            // ATTN
    stage = 4; bh = wg - 246;
    preW(wA, p.Wc, 400, 400, 30, 0, 0, 1, tid);
    int* cidl = (int*)(smem + CID_OFS);
    for (int i = tid; i < 64*UUc; i += 512) {
      const int b = i / UUc, u = i - UUc*b;
      cidl[i] = p.cid[(size_t)(bh*64 + b)*UUc + u] & 63;
    }
    for (int i = tid; i < 640; i += 512) smem[KAP_OFS + i] = 0.f;
  }

  unsigned target = 256;
  gbar(cnt, target, tid);

  for (int s = 0; s < TT + 4; ++s) {
    if (stage == 0) {                               // GRU2, t = s-2
      const int t = s - 2;
      if (t >= 0 && t < TT) {
        Seg segA[2] = { { p.h1r + (size_t)(t & 7)*HH*BB, HH, 1 },
                        { p.wr  + (size_t)(t & 7)*AAc*BB, AAc, 1 } };
        Seg segB    = { p.h2r + (size_t)((t - 1) & 7)*HH*BB, HH, 0 };
        run_gemm<7>(segA, 2, 464, segB, 400, wA, wA + (size_t)rows*464,
                    rows, 4, bh, tid, smem, 28);
        gru_combine(p, 2, t, bh, rr0, R, smem + SM_G, 28, p.bi2, p.bh2,
                    p.h2r + (size_t)((t - 1) & 7)*HH*BB,
                    p.h2r + (size_t)(t & 7)*HH*BB, nullptr, tid);
      }
    } else if (stage == 1) {                        // GRU3, t = s-3
      const int t = s - 3;
      if (t >= 0 && t < TT) {
        Seg segA[2] = { { p.h2r + (size_t)(t & 7)*HH*BB, HH, 1 },
                        { p.wr  + (size_t)(t & 7)*AAc*BB, AAc, 1 } };
        Seg segB    = { p.h3r + (size_t)((t - 1) & 7)*HH*BB, HH, 0 };
        run_gemm<7>(segA, 2, 464, segB, 400, wA, wA + (size_t)rows*464,
                    rows, 4, bh, tid, smem, 28);
        gru_combine(p, 3, t, bh, rr0, R, smem + SM_G, 28, p.bi3, p.bh3,
                    p.h3r + (size_t)((t - 1) & 7)*HH*BB,
                    p.h3r + (size_t)(t & 7)*HH*BB, nullptr, tid);
      }
    } else if (stage == 2) {                        // GRU1, t = s
      const int t = s;
      if (t < TT) {
        Seg segA[1] = { { nullptr, 0, 0 } };
        Seg segB    = { p.h1r + (size_t)((t - 1) & 7)*HH*BB, HH, 0 };
        run_gemm<7>(segA, 1, 0, segB, 400, wA, wA,
                    rows, 0, bh, tid, smem, 0);
        gru_combine(p, 1, t, bh, rr0, R, smem + SM_G, 0, p.bi1, p.bh1,
                    p.h1r + (size_t)((t - 1) & 7)*HH*BB,
                    p.h1r + (size_t)(t & 7)*HH*BB, smem + WI1C_OFS, tid);
      }
    } else if (stage == 3) {                        // OUT, t = s-4
      const int t = s - 4;
      if (t >= 0 && t < TT) {
        Seg segA[4] = { { p.h3r + (size_t)(t & 7)*HH*BB, HH, 1 },
                        { p.h2r + (size_t)(t & 7)*HH*BB, HH, 1 },
                        { p.h1r + (size_t)(t & 7)*HH*BB, HH, 1 },
                        { p.wr  + (size_t)(t & 7)*AAc*BB, AAc, 1 } };
        Seg segB    = { nullptr, 0, 0 };
        run_gemm<2>(segA, 4, 1264, segB, 0, wA, wA,
                    rows, 8, bh, tid, smem, 28);
        out_store(p, t, bh, j0, rows, smem + SM_G, tid);
      }
    } else if (stage == 4) {                        // ATTN, t = s-1
      const int t = s - 1;
      if (t >= 0 && t < TT) {
        Seg segA[1] = { { p.h1r + (size_t)(t & 7)*HH*BB, HH, 0 } };
        Seg segB    = { nullptr, 0, 0 };
        run_gemm<4>(segA, 1, 400, segB, 0, wA, wA,
                    30, 8, bh, tid, smem, 28);
        attn_post(p, t, bh, smem, tid);
      }
    }
    target += 256;
    gbar(cnt, target, tid);
  }
}

extern "C" void kernel_launch(void* const* d_in, const int* in_sizes, int n_in,
                              void* d_out, int out_size, void* d_ws, size_t ws_size,
                              hipStream_t stream)
{
  (void)in_sizes; (void)n_in; (void)out_size; (void)ws_size;
  Params p;
  p.seq = (const float*)d_in[0];
  p.cid = (const int*)  d_in[1];
  p.Wi1 = (const float*)d_in[2];  p.Wh1 = (const float*)d_in[3];
  p.bi1 = (const float*)d_in[4];  p.bh1 = (const float*)d_in[5];
  p.Wc  = (const float*)d_in[6];  p.bc  = (const float*)d_in[7];
  p.Wi2 = (const float*)d_in[8];  p.Wh2 = (const float*)d_in[9];
  p.bi2 = (const float*)d_in[10]; p.bh2 = (const float*)d_in[11];
  p.Wi3 = (const float*)d_in[12]; p.Wh3 = (const float*)d_in[13];
  p.bi3 = (const float*)d_in[14]; p.bh3 = (const float*)d_in[15];
  p.Wl  = (const float*)d_in[16]; p.bl  = (const float*)d_in[17];
  p.out = (float*)d_out;

  float* ws = (float*)d_ws;
  p.bar = (unsigned*)ws;                 // 256 B reserved
  p.h1r = ws + 64;
  p.h2r = p.h1r + (size_t)8*HH*BB;
  p.h3r = p.h2r + (size_t)8*HH*BB;
  p.wr  = p.h3r + (size_t)8*HH*BB;

  hipMemsetAsync(d_ws, 0, 256, stream);  // zero barrier counter (ws is poisoned)

  hipFuncSetAttribute(reinterpret_cast<const void*>(hwnet_kernel),
                      hipFuncAttributeMaxDynamicSharedMemorySize, SM_TOT*4);

  void* args[] = { &p };
  hipLaunchCooperativeKernel(reinterpret_cast<void*>(hwnet_kernel),
                             dim3(256), dim3(512), args, SM_TOT*4, stream);
}

// Round 3
// 12222.595 us; speedup vs baseline: 4.6822x; 2.4333x over previous
//
#include <hip/hip_runtime.h>

#define TT 500
#define S1 (52*128*8)   // xb1 slot elems (416 k-rows = 52 octets)
#define S2 (50*128*8)   // xb2/xb3 slot elems (400 k-rows)
#define SW (8*128*8)    // wring slot elems (64 k-rows)

// dynamic LDS (floats)
#define G_P   0          // 128*68 partial-exchange           [GRU2/3, OUT]
#define G_HP  8704       // 16*128 persistent fp32 h-state    [GRU roles]
#define A_AL  0          // 30*132                            [ATTN]
#define A_PH  3960       // 50*132
#define A_WR  10560      // 64*132
#define A_KAP 19008      // 10*128 persistent kappa
#define A_CID 20288      // 128*50 ints
#define A_BC  26688      // 30
#define SMEMF 26720

typedef __attribute__((ext_vector_type(8))) short short8;
typedef __attribute__((ext_vector_type(4))) short short4v;
typedef __attribute__((ext_vector_type(4))) float f32x4;

#define MFMA16(A,B,C) __builtin_amdgcn_mfma_f32_16x16x32_bf16((A),(B),(C),0,0,0)

struct Params {
  const float* seq; const int* cid;
  const float *Wi1,*Wh1,*bi1,*bh1;
  const float *Wc,*bc;
  const float *Wi2,*Wh2,*bi2,*bh2;
  const float *Wi3,*Wh3,*bi3,*bh3;
  const float *Wl,*bl;
  float* out;
  unsigned* bar;
  unsigned short *xb1, *xb2, *xb3, *wr;   // bf16 payload, swizzled [k>>3][n][k&7]
};

__device__ __forceinline__ short rneb(float f) {
  union { float f; unsigned u; } c; c.f = f;
  unsigned u = c.u;
  return (short)((u + 0x7FFFu + ((u >> 16) & 1u)) >> 16);
}
__device__ __forceinline__ float sigm(float x) { return 1.f / (1.f + expf(-x)); }
__device__ __forceinline__ short8 ld8(const unsigned short* b, int o, int n) {
  return *(const short8*)(b + (size_t)(o*128 + n)*8);
}
__device__ __forceinline__ short8 relu8(short8 v) { short8 s = v >> 15; return v & ~s; }

__device__ __forceinline__ void gbar(unsigned* cnt, unsigned target, int tid) {
  __syncthreads();
  if (tid == 0) {
    __threadfence();
    __hip_atomic_fetch_add(cnt, 1u, __ATOMIC_RELAXED, __HIP_MEMORY_SCOPE_AGENT);
    while (__hip_atomic_load(cnt, __ATOMIC_RELAXED, __HIP_MEMORY_SCOPE_AGENT) < target)
      __builtin_amdgcn_s_sleep(1);
    __threadfence();
  }
  __syncthreads();
}

__device__ __forceinline__ void writeX(const Params& p, int tn, int tid) {
  if (tn >= TT) return;
  unsigned short* dst = p.xb1 + (size_t)(tn & 7) * S1;
  if (tid < 128) {
    int n = tid;
    const float* s = p.seq + ((size_t)tn*128 + n)*3;
    short8 v = { rneb(s[0]), rneb(s[1]), rneb(s[2]), 0,0,0,0,0 };
    *(short8*)(dst + (size_t)(50*128 + n)*8) = v;
  } else if (tid < 256) {
    int n = tid - 128;
    short8 z = {0,0,0,0,0,0,0,0};
    *(short8*)(dst + (size_t)(51*128 + n)*8) = z;
  }
}

__global__ __launch_bounds__(512, 2) void hwnet_kernel(Params p)
{
  extern __shared__ float sm[];
  const int wg = blockIdx.x, tid = threadIdx.x;
  const int lane = tid & 63, wv = tid >> 6;
  const int quad = lane >> 4, col = lane & 15;

  int role, hj = 0, q = 0;
  if      (wg < 25) { role = 0; hj = wg; }        // GRU1
  else if (wg < 50) { role = 1; hj = wg - 25; }   // GRU2
  else if (wg < 75) { role = 2; hj = wg - 50; }   // GRU3
  else if (wg < 79) { role = 3; q  = wg - 75; }   // OUT
  else              { role = 4; }                  // ATTN

  const int kh = wv >> 2, npair = wv & 3;
  const f32x4 z4 = {0.f, 0.f, 0.f, 0.f};

  short8 wfa[42];
  short8 wfx = {0,0,0,0,0,0,0,0};

  // ---------------- one-time preload of weight fragments into registers ----------------
  if (role == 1 || role == 2) {
    const float* Wi = (role == 1) ? p.Wi2 : p.Wi3;
    const float* Wh = (role == 1) ? p.Wh2 : p.Wh3;
#pragma unroll
    for (int rt = 0; rt < 3; ++rt) {
      const int grow = rt*400 + hj*16 + col;
      const float* wi = Wi + (size_t)grow * 464;
      const float* wh = Wh + (size_t)grow * 400;
      if (kh == 0) {
#pragma unroll
        for (int ktl = 0; ktl < 14; ++ktl) {
          short8 f;
#pragma unroll
          for (int j = 0; j < 8; ++j) {
            int k = ktl*32 + quad*8 + j;                 // <448, all in Wi range
            f[j] = rneb(wi[k]);
          }
          wfa[rt*14 + ktl] = f;
        }
      } else {
#pragma unroll
        for (int ktl = 0; ktl < 13; ++ktl) {
          short8 f;
#pragma unroll
          for (int j = 0; j < 8; ++j) {
            int k = (14 + ktl)*32 + quad*8 + j;
            float v = (k < 464) ? wi[k] : wh[k - 464];
            if (rt == 2 && ktl == 0 && k < 464) v = 0.f; // n-gate: hi(B)-part only
            f[j] = rneb(v);
          }
          wfa[rt*14 + ktl] = f;
        }
      }
    }
    if (kh == 1) {  // n-gate lo(A)-part of boundary ktile 14
      const int grow = 2*400 + hj*16 + col;
      const float* wi = Wi + (size_t)grow * 464;
      short8 f;
#pragma unroll
      for (int j = 0; j < 8; ++j) {
        int k = 14*32 + quad*8 + j;
        f[j] = rneb((k < 464) ? wi[k] : 0.f);
      }
      wfx = f;
    }
  } else if (role == 0) {
#pragma unroll
    for (int rt = 0; rt < 3; ++rt) {
      const int grow = rt*400 + hj*16 + col;
      const float* whr = p.Wh1 + (size_t)grow * 400;
      const float* wir = p.Wi1 + (size_t)grow * 67;
#pragma unroll
      for (int ktl = 0; ktl < 13; ++ktl) {
        short8 f;
#pragma unroll
        for (int j = 0; j < 8; ++j) {
          int k = ktl*32 + quad*8 + j;
          float v = 0.f;
          if (k < 400) v = whr[k];
          else if (k < 403) v = wir[k - 400];
          if (rt == 2 && ktl == 12 && k >= 400) v = 0.f; // n-gate: lo(B)-part only
          f[j] = rneb(v);
        }
        wfa[rt*14 + ktl] = f;
      }
    }
    { // n-gate hi(A = x-cols) part of boundary ktile 12
      const int grow = 2*400 + hj*16 + col;
      const float* wir = p.Wi1 + (size_t)grow * 67;
      short8 f;
#pragma unroll
      for (int j = 0; j < 8; ++j) {
        int k = 12*32 + quad*8 + j;
        f[j] = rneb((k >= 400 && k < 403) ? wir[k - 400] : 0.f);
      }
      wfx = f;
    }
  } else if (role == 3) {
#pragma unroll
    for (int rt = 0; rt < 2; ++rt) {
      const int grow = q*32 + rt*16 + col;
      const float* wl = p.Wl + (size_t)grow * 1264;
#pragma unroll
      for (int ktl = 0; ktl < 20; ++ktl) {
        short8 f;
#pragma unroll
        for (int j = 0; j < 8; ++j) {
          int k = (kh*20 + ktl)*32 + quad*8 + j;
          f[j] = rneb((grow < 121 && k < 1264) ? wl[k] : 0.f);
        }
        wfa[rt*20 + ktl] = f;
      }
    }
  } else { // ATTN
#pragma unroll
    for (int rt = 0; rt < 2; ++rt) {
      const int grow = rt*16 + col;
      const float* wc = p.Wc + (size_t)grow * 400;
#pragma unroll
      for (int ktl = 0; ktl < 13; ++ktl) {
        short8 f;
#pragma unroll
        for (int j = 0; j < 8; ++j) {
          int k = ktl*32 + quad*8 + j;
          f[j] = rneb((grow < 30 && k < 400) ? wc[k] : 0.f);
        }
        wfa[rt*13 + ktl] = f;
      }
    }
    int* cidl = (int*)(sm + A_CID);
    for (int i = tid; i < 128*50; i += 512) cidl[i] = p.cid[i] & 63;
    for (int i = tid; i < 1280; i += 512) sm[A_KAP + i] = 0.f;
    for (int i = tid; i < 30; i += 512) sm[A_BC + i] = p.bc[i];
  }

  // biases into registers
  float bR[4], bZ[4], bNi[4], bNh[4], blr[8];
  if (role < 3) {
    const float* bi = role == 0 ? p.bi1 : role == 1 ? p.bi2 : p.bi3;
    const float* bh = role == 0 ? p.bh1 : role == 1 ? p.bh2 : p.bh3;
#pragma unroll
    for (int r = 0; r < 4; ++r) {
      int row = hj*16 + quad*4 + r;
      bR[r]  = bi[row] + bh[row];
      bZ[r]  = bi[400 + row] + bh[400 + row];
      bNi[r] = bi[800 + row];
      bNh[r] = bh[800 + row];
    }
    for (int i = tid; i < 2048; i += 512) sm[G_HP + i] = 0.f;
  }
  if (role == 3) {
#pragma unroll
    for (int rt = 0; rt < 2; ++rt)
#pragma unroll
      for (int r = 0; r < 4; ++r) {
        int row = q*32 + rt*16 + quad*4 + r;
        blr[rt*4 + r] = (row < 121) ? p.bl[row] : 0.f;
      }
  }

  // zero t=-1 ring content (ws is poisoned every launch)
  if (role == 0) {
    unsigned* b0 = (unsigned*)(p.xb1 + (size_t)hj*2*128*8);
    for (int i = tid; i < 1024; i += 512) b0[i] = 0u;
    if (hj == 0) writeX(p, 0, tid);
  } else if (role == 1) {
    unsigned* b0 = (unsigned*)(p.xb2 + (size_t)hj*2*128*8);
    for (int i = tid; i < 1024; i += 512) b0[i] = 0u;
  } else if (role == 2) {
    unsigned* b0 = (unsigned*)(p.xb3 + (size_t)hj*2*128*8);
    for (int i = tid; i < 1024; i += 512) b0[i] = 0u;
  }

  gbar(p.bar, 80u, tid);

  // ---------------- skewed pipeline main loop ----------------
  for (int s = 0; s < TT + 4; ++s) {
    if (role == 1 || role == 2) {                      // GRU2 (t=s-2) / GRU3 (t=s-3)
      const int t = s - (role == 1 ? 2 : 3);
      if (t >= 0 && t < TT) {
        const unsigned short* srcRelu = (role == 1 ? p.xb1 : p.xb2) + (size_t)((t+1)&7) * (role == 1 ? S1 : S2);
        const unsigned short* wrs     = p.wr + (size_t)(t&7) * SW;
        const unsigned short* srcOwn  = (role == 1 ? p.xb2 : p.xb3) + (size_t)(t&7) * S2;
        unsigned short*       dstW    = (role == 1 ? p.xb2 : p.xb3) + (size_t)((t+1)&7) * S2;
        f32x4 aR[2] = {z4, z4}, aZ[2] = {z4, z4}, aN[2] = {z4, z4}, aNB[2] = {z4, z4};
#pragma unroll
        for (int nt = 0; nt < 2; ++nt) {
          const int n = npair*32 + nt*16 + col;
          if (kh == 0) {
#pragma unroll
            for (int c2 = 0; c2 < 2; ++c2) {
              short8 bf[7];
#pragma unroll
              for (int i = 0; i < 7; ++i) {
                int o = (c2*7 + i)*4 + quad;
                bf[i] = (o < 50) ? relu8(ld8(srcRelu, o, n)) : ld8(wrs, o - 50, n);
              }
#pragma unroll
              for (int i = 0; i < 7; ++i) {
                int kt = c2*7 + i;
                aR[nt] = MFMA16(wfa[kt],      bf[i], aR[nt]);
                aZ[nt] = MFMA16(wfa[14 + kt], bf[i], aZ[nt]);
                aN[nt] = MFMA16(wfa[28 + kt], bf[i], aN[nt]);
              }
            }
          } else {
#pragma unroll
            for (int c2 = 0; c2 < 2; ++c2) {
              const int cn = c2 ? 6 : 7;
              short8 bf[7];
#pragma unroll
              for (int i = 0; i < 7; ++i) if (i < cn) {
                int o = (14 + c2*7 + i)*4 + quad;
                bf[i] = (o < 58) ? ld8(wrs, o - 50, n) : ld8(srcOwn, o - 58, n);
              }
#pragma unroll
              for (int i = 0; i < 7; ++i) if (i < cn) {
                int ktl = c2*7 + i;
                aR[nt]  = MFMA16(wfa[ktl],      bf[i], aR[nt]);
                aZ[nt]  = MFMA16(wfa[14 + ktl], bf[i], aZ[nt]);
                aNB[nt] = MFMA16(wfa[28 + ktl], bf[i], aNB[nt]);
                if (ktl == 0) aN[nt] = MFMA16(wfx, bf[i], aN[nt]);
              }
            }
          }
        }
        float* P = sm + G_P;
        if (kh == 1) {
#pragma unroll
          for (int nt = 0; nt < 2; ++nt) {
            int cg = npair*32 + nt*16 + col;
            float* pc = P + cg*68 + quad*4;
            *(f32x4*)(pc)      = aR[nt];
            *(f32x4*)(pc + 16) = aZ[nt];
            *(f32x4*)(pc + 32) = aN[nt];
            *(f32x4*)(pc + 48) = aNB[nt];
          }
        }
        __syncthreads();
        if (kh == 0) {
#pragma unroll
          for (int nt = 0; nt < 2; ++nt) {
            int cg = npair*32 + nt*16 + col;
            const float* pc = P + cg*68 + quad*4;
            f32x4 pR  = *(const f32x4*)(pc);
            f32x4 pZ  = *(const f32x4*)(pc + 16);
            f32x4 pNA = *(const f32x4*)(pc + 32);
            f32x4 pNB = *(const f32x4*)(pc + 48);
            short hq[4];
#pragma unroll
            for (int r = 0; r < 4; ++r) {
              float R  = aR[nt][r] + pR[r] + bR[r];
              float Z  = aZ[nt][r] + pZ[r] + bZ[r];
              float NA = aN[nt][r] + pNA[r] + bNi[r];
              float NB = pNB[r] + bNh[r];
              float rg = sigm(R), zg = sigm(Z);
              float ng = tanhf(NA + rg*NB);
              int m = quad*4 + r;
              float hpv = sm[G_HP + m*128 + cg];
              float h = (1.f - zg)*ng + zg*hpv;
              sm[G_HP + m*128 + cg] = h;
              hq[r] = rneb(h);
            }
            short4v hv = {hq[0], hq[1], hq[2], hq[3]};
            *(short4v*)(dstW + (size_t)((hj*2 + (quad >> 1))*128 + cg)*8 + (quad & 1)*4) = hv;
          }
        }
      }
    } else if (role == 0) {                            // GRU1, t = s
      const int t = s;
      if (t < TT) {
        const unsigned short* src = p.xb1 + (size_t)(t&7) * S1;
        unsigned short* dstW = p.xb1 + (size_t)((t+1)&7) * S1;
        f32x4 aR = z4, aZ = z4, aNA = z4, aNB = z4;
        const int n = wv*16 + col;
#pragma unroll
        for (int c2 = 0; c2 < 2; ++c2) {
          const int cn = c2 ? 6 : 7;
          short8 bf[7];
#pragma unroll
          for (int i = 0; i < 7; ++i) if (i < cn) bf[i] = ld8(src, (c2*7 + i)*4 + quad, n);
#pragma unroll
          for (int i = 0; i < 7; ++i) if (i < cn) {
            int kt = c2*7 + i;
            aR  = MFMA16(wfa[kt],      bf[i], aR);
            aZ  = MFMA16(wfa[14 + kt], bf[i], aZ);
            aNB = MFMA16(wfa[28 + kt], bf[i], aNB);
            if (kt == 12) aNA = MFMA16(wfx, bf[i], aNA);
          }
        }
        short hq[4];
#pragma unroll
        for (int r = 0; r < 4; ++r) {
          float rg = sigm(aR[r] + bR[r]);
          float zg = sigm(aZ[r] + bZ[r]);
          float ng = tanhf(aNA[r] + bNi[r] + rg*(aNB[r] + bNh[r]));
          int m = quad*4 + r;
          float hpv = sm[G_HP + m*128 + n];
          float h = (1.f - zg)*ng + zg*hpv;
          sm[G_HP + m*128 + n] = h;
          hq[r] = rneb(h);
        }
        short4v hv = {hq[0], hq[1], hq[2], hq[3]};
        *(short4v*)(dstW + (size_t)((hj*2 + (quad >> 1))*128 + n)*8 + (quad & 1)*4) = hv;
        if (hj == 0) writeX(p, t + 1, tid);
      }
    } else if (role == 3) {                            // OUT, t = s-4
      const int t = s - 4;
      if (t >= 0 && t < TT) {
        const unsigned short* s3p = p.xb3 + (size_t)((t+1)&7) * S2;
        const unsigned short* s2p = p.xb2 + (size_t)((t+1)&7) * S2;
        const unsigned short* s1p = p.xb1 + (size_t)((t+1)&7) * S1;
        const unsigned short* wrs = p.wr + (size_t)(t&7) * SW;
        f32x4 a0[2] = {z4, z4}, a1[2] = {z4, z4};
#pragma unroll
        for (int nt = 0; nt < 2; ++nt) {
          const int n = npair*32 + nt*16 + col;
#pragma unroll
          for (int c2 = 0; c2 < 2; ++c2) {
            short8 bf[10];
#pragma unroll
            for (int i = 0; i < 10; ++i) {
              int o = (kh*20 + c2*10 + i)*4 + quad;
              short8 v;
              if      (o < 50)  v = relu8(ld8(s3p, o, n));
              else if (o < 100) v = relu8(ld8(s2p, o - 50, n));
              else if (o < 150) v = relu8(ld8(s1p, o - 100, n));
              else if (o < 158) v = ld8(wrs, o - 150, n);
              else { short8 zz = {0,0,0,0,0,0,0,0}; v = zz; }
              bf[i] = v;
            }
#pragma unroll
            for (int i = 0; i < 10; ++i) {
              int ktl = c2*10 + i;
              a0[nt] = MFMA16(wfa[ktl],      bf[i], a0[nt]);
              a1[nt] = MFMA16(wfa[20 + ktl], bf[i], a1[nt]);
            }
          }
        }
        float* P = sm + G_P;
        if (kh == 1) {
#pragma unroll
          for (int nt = 0; nt < 2; ++nt) {
            int cg = npair*32 + nt*16 + col;
            float* pc = P + cg*68 + quad*4;
            *(f32x4*)(pc)      = a0[nt];
            *(f32x4*)(pc + 16) = a1[nt];
          }
        }
        __syncthreads();
        if (kh == 0) {
#pragma unroll
          for (int nt = 0; nt < 2; ++nt) {
            int cg = npair*32 + nt*16 + col;
            const float* pc = P + cg*68 + quad*4;
            f32x4 p0 = *(const f32x4*)(pc);
            f32x4 p1 = *(const f32x4*)(pc + 16);
#pragma unroll
            for (int rt = 0; rt < 2; ++rt)
#pragma unroll
              for (int r = 0; r < 4; ++r) {
                int row = q*32 + rt*16 + quad*4 + r;
                float v = (rt ? a1[nt][r] + p1[r] : a0[nt][r] + p0[r]) + blr[rt*4 + r];
                if (row < 121) p.out[((size_t)cg*TT + t)*121 + row] = v;
              }
          }
        }
      }
    } else {                                           // ATTN, t = s-1
      const int t = s - 1;
      if (t >= 0 && t < TT) {
        const unsigned short* src = p.xb1 + (size_t)((t+1)&7) * S1;
        unsigned short* wdst = p.wr + (size_t)(t&7) * SW;
        f32x4 a0 = z4, a1 = z4;
        const int n = wv*16 + col;
#pragma unroll
        for (int c2 = 0; c2 < 2; ++c2) {
          const int cn = c2 ? 6 : 7;
          short8 bf[7];
#pragma unroll
          for (int i = 0; i < 7; ++i) if (i < cn) bf[i] = ld8(src, (c2*7 + i)*4 + quad, n);
#pragma unroll
          for (int i = 0; i < 7; ++i) if (i < cn) {
            int kt = c2*7 + i;
            a0 = MFMA16(wfa[kt],      bf[i], a0);
            a1 = MFMA16(wfa[13 + kt], bf[i], a1);
          }
        }
#pragma unroll
        for (int rt = 0; rt < 2; ++rt)
#pragma unroll
          for (int r = 0; r < 4; ++r) {
            int row = rt*16 + quad*4 + r;
            if (row < 30) sm[A_AL + row*132 + n] = (rt ? a1[r] : a0[r]);
          }
        __syncthreads();
        for (int idx = tid; idx < 30*128; idx += 512) {
          int l = idx >> 7, b = idx & 127;
          float v = expf(sm[A_AL + l*132 + b] + sm[A_BC + l]);
          if (l >= 20) { float kk = sm[A_KAP + (l-20)*128 + b] + v; sm[A_KAP + (l-20)*128 + b] = kk; v = kk; }
          sm[A_AL + l*132 + b] = v;
        }
        __syncthreads();
        for (int idx = tid; idx < 50*128; idx += 512) {
          int u = idx >> 7, b = idx & 127;
          float ph = 0.f;
#pragma unroll
          for (int j = 0; j < 10; ++j) {
            float al = sm[A_AL + j*132 + b];
            float be = sm[A_AL + (10 + j)*132 + b];
            float ka = sm[A_AL + (20 + j)*132 + b];
            float d = ka - (float)u;
            ph += al * expf(-be*d*d);
          }
          sm[A_PH + u*132 + b] = ph;
        }
        __syncthreads();
        for (int i = tid; i < 64*132; i += 512) sm[A_WR + i] = 0.f;
        __syncthreads();
        if (tid < 128) {
          int b = tid;
          const int* cidl = (const int*)(sm + A_CID);
          for (int u = 0; u < 50; ++u)
            sm[A_WR + cidl[b*50 + u]*132 + b] += sm[A_PH + u*132 + b];
        }
        __syncthreads();
        for (int idx = tid; idx < 8*128; idx += 512) {
          int o = idx >> 7, b = idx & 127;
          short8 v;
#pragma unroll
          for (int e = 0; e < 8; ++e) v[e] = rneb(sm[A_WR + (o*8 + e)*132 + b]);
          *(short8*)(wdst + (size_t)(o*128 + b)*8) = v;
        }
      }
    }
    gbar(p.bar, 80u*(unsigned)(s + 2), tid);
  }
}

extern "C" void kernel_launch(void* const* d_in, const int* in_sizes, int n_in,
                              void* d_out, int out_size, void* d_ws, size_t ws_size,
                              hipStream_t stream)
{
  (void)in_sizes; (void)n_in; (void)out_size; (void)ws_size;
  Params p;
  p.seq = (const float*)d_in[0];
  p.cid = (const int*)  d_in[1];
  p.Wi1 = (const float*)d_in[2];  p.Wh1 = (const float*)d_in[3];
  p.bi1 = (const float*)d_in[4];  p.bh1 = (const float*)d_in[5];
  p.Wc  = (const float*)d_in[6];  p.bc  = (const float*)d_in[7];
  p.Wi2 = (const float*)d_in[8];  p.Wh2 = (const float*)d_in[9];
  p.bi2 = (const float*)d_in[10]; p.bh2 = (const float*)d_in[11];
  p.Wi3 = (const float*)d_in[12]; p.Wh3 = (const float*)d_in[13];
  p.bi3 = (const float*)d_in[14]; p.bh3 = (const float*)d_in[15];
  p.Wl  = (const float*)d_in[16]; p.bl  = (const float*)d_in[17];
  p.out = (float*)d_out;

  char* ws = (char*)d_ws;
  p.bar = (unsigned*)ws;                      ws += 256;
  p.xb1 = (unsigned short*)ws;                ws += (size_t)8 * S1 * 2;
  p.xb2 = (unsigned short*)ws;                ws += (size_t)8 * S2 * 2;
  p.xb3 = (unsigned short*)ws;                ws += (size_t)8 * S2 * 2;
  p.wr  = (unsigned short*)ws;                ws += (size_t)8 * SW * 2;

  hipMemsetAsync(d_ws, 0, 256, stream);       // zero barrier counter (ws is poisoned)

  hipFuncSetAttribute(reinterpret_cast<const void*>(hwnet_kernel),
                      hipFuncAttributeMaxDynamicSharedMemorySize, SMEMF * 4);

  void* args[] = { &p };
  hipLaunchCooperativeKernel(reinterpret_cast<void*>(hwnet_kernel),
                             dim3(80), dim3(512), args, SMEMF * 4, stream);
}

// Round 4
// 11102.509 us; speedup vs baseline: 5.1546x; 1.1009x over previous
//
#include <hip/hip_runtime.h>

#define TT 500
#define S1 (52*128*8)   // xb1 slot elems (416 k-rows = 52 octets)
#define S2 (50*128*8)   // xb2/xb3 slot elems (400 k-rows)
#define SW (8*128*8)    // wring slot elems (64 k-rows)

// dynamic LDS (floats)
#define G_P   0          // 128*68 partial-exchange           [GRU2/3, OUT]
#define G_HP  8704       // 16*128 persistent fp32 h-state    [GRU roles]
#define A_AL  0          // 30*132                            [ATTN]
#define A_PH  3960       // 50*132
#define A_WR  10560      // 64*132
#define A_KAP 19008      // 10*128 persistent kappa
#define A_CID 20288      // 128*50 ints
#define A_BC  26688      // 30
#define SMEMF 26720

typedef __attribute__((ext_vector_type(8))) short short8;
typedef __attribute__((ext_vector_type(4))) short short4v;
typedef __attribute__((ext_vector_type(4))) float f32x4;
typedef unsigned long long u64;

#define MFMA16(A,B,C) __builtin_amdgcn_mfma_f32_16x16x32_bf16((A),(B),(C),0,0,0)

struct Params {
  const float* seq; const int* cid;
  const float *Wi1,*Wh1,*bi1,*bh1;
  const float *Wc,*bc;
  const float *Wi2,*Wh2,*bi2,*bh2;
  const float *Wi3,*Wh3,*bi3,*bh3;
  const float *Wl,*bl;
  float* out;
  unsigned* bar;
  unsigned short *xb1, *xb2, *xb3, *wr;   // bf16 payload, swizzled [k>>3][n][k&7]
};

__device__ __forceinline__ short rneb(float f) {
  union { float f; unsigned u; } c; c.f = f;
  unsigned u = c.u;
  return (short)((u + 0x7FFFu + ((u >> 16) & 1u)) >> 16);
}
__device__ __forceinline__ float sigm(float x) { return 1.f / (1.f + expf(-x)); }

// Cross-WG payload: agent-scope relaxed atomics -> sc1-flagged loads/stores that
// bypass the (non-cross-XCD-coherent) L2 and hit the shared coherence point.
// No buffer_wbl2 / buffer_inv needed anywhere.
__device__ __forceinline__ short8 ld8(const unsigned short* b, int o, int n) {
  const u64* q = (const u64*)(b + (size_t)(o*128 + n)*8);
  union { u64 u[2]; short8 s; } c;
  c.u[0] = __hip_atomic_load(q,     __ATOMIC_RELAXED, __HIP_MEMORY_SCOPE_AGENT);
  c.u[1] = __hip_atomic_load(q + 1, __ATOMIC_RELAXED, __HIP_MEMORY_SCOPE_AGENT);
  return c.s;
}
__device__ __forceinline__ void st8(unsigned short* b, int o, int n, short8 v) {
  u64* q = (u64*)(b + (size_t)(o*128 + n)*8);
  union { short8 s; u64 u[2]; } c; c.s = v;
  __hip_atomic_store(q,     c.u[0], __ATOMIC_RELAXED, __HIP_MEMORY_SCOPE_AGENT);
  __hip_atomic_store(q + 1, c.u[1], __ATOMIC_RELAXED, __HIP_MEMORY_SCOPE_AGENT);
}
__device__ __forceinline__ void st4(unsigned short* addr, short4v v) {
  union { short4v s; u64 u; } c; c.s = v;
  __hip_atomic_store((u64*)addr, c.u, __ATOMIC_RELAXED, __HIP_MEMORY_SCOPE_AGENT);
}
__device__ __forceinline__ short8 relu8(short8 v) { short8 s = v >> 15; return v & ~s; }

// Grid barrier, fence-free: payload is already sc1 (write-through to coherence
// point); s_waitcnt vmcnt(0) in every thread guarantees acks before arrival.
__device__ __forceinline__ void gbar(unsigned* cnt, unsigned target, int tid) {
  __builtin_amdgcn_s_waitcnt(0);
  __syncthreads();
  if (tid == 0) {
    __hip_atomic_fetch_add(cnt, 1u, __ATOMIC_RELAXED, __HIP_MEMORY_SCOPE_AGENT);
    while (__hip_atomic_load(cnt, __ATOMIC_RELAXED, __HIP_MEMORY_SCOPE_AGENT) < target)
      __builtin_amdgcn_s_sleep(1);
  }
  __syncthreads();
}

__device__ __forceinline__ void writeX(const Params& p, int tn, int tid) {
  if (tn >= TT) return;
  unsigned short* dst = p.xb1 + (size_t)(tn & 7) * S1;
  if (tid < 128) {
    int n = tid;
    const float* s = p.seq + ((size_t)tn*128 + n)*3;
    short8 v = { rneb(s[0]), rneb(s[1]), rneb(s[2]), 0,0,0,0,0 };
    st8(dst, 50, n, v);
  } else if (tid < 256) {
    int n = tid - 128;
    short8 z = {0,0,0,0,0,0,0,0};
    st8(dst, 51, n, z);
  }
}

__global__ __launch_bounds__(512, 2) void hwnet_kernel(Params p)
{
  extern __shared__ float sm[];
  const int wg = blockIdx.x, tid = threadIdx.x;
  const int lane = tid & 63, wv = tid >> 6;
  const int quad = lane >> 4, col = lane & 15;

  int role, hj = 0, q = 0;
  if      (wg < 25) { role = 0; hj = wg; }        // GRU1
  else if (wg < 50) { role = 1; hj = wg - 25; }   // GRU2
  else if (wg < 75) { role = 2; hj = wg - 50; }   // GRU3
  else if (wg < 79) { role = 3; q  = wg - 75; }   // OUT
  else              { role = 4; }                  // ATTN

  const int kh = wv >> 2, npair = wv & 3;
  const f32x4 z4 = {0.f, 0.f, 0.f, 0.f};

  short8 wfa[42];
  short8 wfx = {0,0,0,0,0,0,0,0};

  // ---------------- one-time preload of weight fragments into registers ----------------
  if (role == 1 || role == 2) {
    const float* Wi = (role == 1) ? p.Wi2 : p.Wi3;
    const float* Wh = (role == 1) ? p.Wh2 : p.Wh3;
#pragma unroll
    for (int rt = 0; rt < 3; ++rt) {
      const int grow = rt*400 + hj*16 + col;
      const float* wi = Wi + (size_t)grow * 464;
      const float* wh = Wh + (size_t)grow * 400;
      if (kh == 0) {
#pragma unroll
        for (int ktl = 0; ktl < 14; ++ktl) {
          short8 f;
#pragma unroll
          for (int j = 0; j < 8; ++j) {
            int k = ktl*32 + quad*8 + j;                 // <448, all in Wi range
            f[j] = rneb(wi[k]);
          }
          wfa[rt*14 + ktl] = f;
        }
      } else {
#pragma unroll
        for (int ktl = 0; ktl < 13; ++ktl) {
          short8 f;
#pragma unroll
          for (int j = 0; j < 8; ++j) {
            int k = (14 + ktl)*32 + quad*8 + j;
            float v = (k < 464) ? wi[k] : wh[k - 464];
            if (rt == 2 && ktl == 0 && k < 464) v = 0.f; // n-gate: hi(B)-part only
            f[j] = rneb(v);
          }
          wfa[rt*14 + ktl] = f;
        }
      }
    }
    if (kh == 1) {  // n-gate lo(A)-part of boundary ktile 14
      const int grow = 2*400 + hj*16 + col;
      const float* wi = Wi + (size_t)grow * 464;
      short8 f;
#pragma unroll
      for (int j = 0; j < 8; ++j) {
        int k = 14*32 + quad*8 + j;
        f[j] = rneb((k < 464) ? wi[k] : 0.f);
      }
      wfx = f;
    }
  } else if (role == 0) {
#pragma unroll
    for (int rt = 0; rt < 3; ++rt) {
      const int grow = rt*400 + hj*16 + col;
      const float* whr = p.Wh1 + (size_t)grow * 400;
      const float* wir = p.Wi1 + (size_t)grow * 67;
#pragma unroll
      for (int ktl = 0; ktl < 13; ++ktl) {
        short8 f;
#pragma unroll
        for (int j = 0; j < 8; ++j) {
          int k = ktl*32 + quad*8 + j;
          float v = 0.f;
          if (k < 400) v = whr[k];
          else if (k < 403) v = wir[k - 400];
          if (rt == 2 && ktl == 12 && k >= 400) v = 0.f; // n-gate: lo(B)-part only
          f[j] = rneb(v);
        }
        wfa[rt*14 + ktl] = f;
      }
    }
    { // n-gate hi(A = x-cols) part of boundary ktile 12
      const int grow = 2*400 + hj*16 + col;
      const float* wir = p.Wi1 + (size_t)grow * 67;
      short8 f;
#pragma unroll
      for (int j = 0; j < 8; ++j) {
        int k = 12*32 + quad*8 + j;
        f[j] = rneb((k >= 400 && k < 403) ? wir[k - 400] : 0.f);
      }
      wfx = f;
    }
  } else if (role == 3) {
#pragma unroll
    for (int rt = 0; rt < 2; ++rt) {
      const int grow = q*32 + rt*16 + col;
      const float* wl = p.Wl + (size_t)grow * 1264;
#pragma unroll
      for (int ktl = 0; ktl < 20; ++ktl) {
        short8 f;
#pragma unroll
        for (int j = 0; j < 8; ++j) {
          int k = (kh*20 + ktl)*32 + quad*8 + j;
          f[j] = rneb((grow < 121 && k < 1264) ? wl[k] : 0.f);
        }
        wfa[rt*20 + ktl] = f;
      }
    }
  } else { // ATTN
#pragma unroll
    for (int rt = 0; rt < 2; ++rt) {
      const int grow = rt*16 + col;
      const float* wc = p.Wc + (size_t)grow * 400;
#pragma unroll
      for (int ktl = 0; ktl < 13; ++ktl) {
        short8 f;
#pragma unroll
        for (int j = 0; j < 8; ++j) {
          int k = ktl*32 + quad*8 + j;
          f[j] = rneb((grow < 30 && k < 400) ? wc[k] : 0.f);
        }
        wfa[rt*13 + ktl] = f;
      }
    }
    int* cidl = (int*)(sm + A_CID);
    for (int i = tid; i < 128*50; i += 512) cidl[i] = p.cid[i] & 63;
    for (int i = tid; i < 1280; i += 512) sm[A_KAP + i] = 0.f;
    for (int i = tid; i < 30; i += 512) sm[A_BC + i] = p.bc[i];
  }

  // biases into registers
  float bR[4], bZ[4], bNi[4], bNh[4], blr[8];
  if (role < 3) {
    const float* bi = role == 0 ? p.bi1 : role == 1 ? p.bi2 : p.bi3;
    const float* bh = role == 0 ? p.bh1 : role == 1 ? p.bh2 : p.bh3;
#pragma unroll
    for (int r = 0; r < 4; ++r) {
      int row = hj*16 + quad*4 + r;
      bR[r]  = bi[row] + bh[row];
      bZ[r]  = bi[400 + row] + bh[400 + row];
      bNi[r] = bi[800 + row];
      bNh[r] = bh[800 + row];
    }
    for (int i = tid; i < 2048; i += 512) sm[G_HP + i] = 0.f;
  }
  if (role == 3) {
#pragma unroll
    for (int rt = 0; rt < 2; ++rt)
#pragma unroll
      for (int r = 0; r < 4; ++r) {
        int row = q*32 + rt*16 + quad*4 + r;
        blr[rt*4 + r] = (row < 121) ? p.bl[row] : 0.f;
      }
  }

  // zero t=-1 ring content via sc1 stores (ws is poisoned every launch)
  if (role == 0) {
    u64* b0 = (u64*)(p.xb1 + (size_t)hj*2*128*8);
    for (int i = tid; i < 512; i += 512)
      __hip_atomic_store(b0 + i, 0ull, __ATOMIC_RELAXED, __HIP_MEMORY_SCOPE_AGENT);
    if (hj == 0) writeX(p, 0, tid);
  } else if (role == 1) {
    u64* b0 = (u64*)(p.xb2 + (size_t)hj*2*128*8);
    for (int i = tid; i < 512; i += 512)
      __hip_atomic_store(b0 + i, 0ull, __ATOMIC_RELAXED, __HIP_MEMORY_SCOPE_AGENT);
  } else if (role == 2) {
    u64* b0 = (u64*)(p.xb3 + (size_t)hj*2*128*8);
    for (int i = tid; i < 512; i += 512)
      __hip_atomic_store(b0 + i, 0ull, __ATOMIC_RELAXED, __HIP_MEMORY_SCOPE_AGENT);
  }

  gbar(p.bar, 80u, tid);

  // ---------------- skewed pipeline main loop ----------------
  for (int s = 0; s < TT + 4; ++s) {
    if (role == 1 || role == 2) {                      // GRU2 (t=s-2) / GRU3 (t=s-3)
      const int t = s - (role == 1 ? 2 : 3);
      if (t >= 0 && t < TT) {
        const unsigned short* srcRelu = (role == 1 ? p.xb1 : p.xb2) + (size_t)((t+1)&7) * (role == 1 ? S1 : S2);
        const unsigned short* wrs     = p.wr + (size_t)(t&7) * SW;
        const unsigned short* srcOwn  = (role == 1 ? p.xb2 : p.xb3) + (size_t)(t&7) * S2;
        unsigned short*       dstW    = (role == 1 ? p.xb2 : p.xb3) + (size_t)((t+1)&7) * S2;
        f32x4 aR[2] = {z4, z4}, aZ[2] = {z4, z4}, aN[2] = {z4, z4}, aNB[2] = {z4, z4};
#pragma unroll
        for (int nt = 0; nt < 2; ++nt) {
          const int n = npair*32 + nt*16 + col;
          if (kh == 0) {
#pragma unroll
            for (int c2 = 0; c2 < 2; ++c2) {
              short8 bf[7];
#pragma unroll
              for (int i = 0; i < 7; ++i) {
                int o = (c2*7 + i)*4 + quad;
                bf[i] = (o < 50) ? relu8(ld8(srcRelu, o, n)) : ld8(wrs, o - 50, n);
              }
#pragma unroll
              for (int i = 0; i < 7; ++i) {
                int kt = c2*7 + i;
                aR[nt] = MFMA16(wfa[kt],      bf[i], aR[nt]);
                aZ[nt] = MFMA16(wfa[14 + kt], bf[i], aZ[nt]);
                aN[nt] = MFMA16(wfa[28 + kt], bf[i], aN[nt]);
              }
            }
          } else {
#pragma unroll
            for (int c2 = 0; c2 < 2; ++c2) {
              const int cn = c2 ? 6 : 7;
              short8 bf[7];
#pragma unroll
              for (int i = 0; i < 7; ++i) if (i < cn) {
                int o = (14 + c2*7 + i)*4 + quad;
                bf[i] = (o < 58) ? ld8(wrs, o - 50, n) : ld8(srcOwn, o - 58, n);
              }
#pragma unroll
              for (int i = 0; i < 7; ++i) if (i < cn) {
                int ktl = c2*7 + i;
                aR[nt]  = MFMA16(wfa[ktl],      bf[i], aR[nt]);
                aZ[nt]  = MFMA16(wfa[14 + ktl], bf[i], aZ[nt]);
                aNB[nt] = MFMA16(wfa[28 + ktl], bf[i], aNB[nt]);
                if (ktl == 0) aN[nt] = MFMA16(wfx, bf[i], aN[nt]);
              }
            }
          }
        }
        float* P = sm + G_P;
        if (kh == 1) {
#pragma unroll
          for (int nt = 0; nt < 2; ++nt) {
            int cg = npair*32 + nt*16 + col;
            float* pc = P + cg*68 + quad*4;
            *(f32x4*)(pc)      = aR[nt];
            *(f32x4*)(pc + 16) = aZ[nt];
            *(f32x4*)(pc + 32) = aN[nt];
            *(f32x4*)(pc + 48) = aNB[nt];
          }
        }
        __syncthreads();
        if (kh == 0) {
#pragma unroll
          for (int nt = 0; nt < 2; ++nt) {
            int cg = npair*32 + nt*16 + col;
            const float* pc = P + cg*68 + quad*4;
            f32x4 pR  = *(const f32x4*)(pc);
            f32x4 pZ  = *(const f32x4*)(pc + 16);
            f32x4 pNA = *(const f32x4*)(pc + 32);
            f32x4 pNB = *(const f32x4*)(pc + 48);
            short hq[4];
#pragma unroll
            for (int r = 0; r < 4; ++r) {
              float R  = aR[nt][r] + pR[r] + bR[r];
              float Z  = aZ[nt][r] + pZ[r] + bZ[r];
              float NA = aN[nt][r] + pNA[r] + bNi[r];
              float NB = pNB[r] + bNh[r];
              float rg = sigm(R), zg = sigm(Z);
              float ng = tanhf(NA + rg*NB);
              int m = quad*4 + r;
              float hpv = sm[G_HP + m*128 + cg];
              float h = (1.f - zg)*ng + zg*hpv;
              sm[G_HP + m*128 + cg] = h;
              hq[r] = rneb(h);
            }
            short4v hv = {hq[0], hq[1], hq[2], hq[3]};
            st4(dstW + (size_t)((hj*2 + (quad >> 1))*128 + cg)*8 + (quad & 1)*4, hv);
          }
        }
      }
    } else if (role == 0) {                            // GRU1, t = s
      const int t = s;
      if (t < TT) {
        const unsigned short* src = p.xb1 + (size_t)(t&7) * S1;
        unsigned short* dstW = p.xb1 + (size_t)((t+1)&7) * S1;
        f32x4 aR = z4, aZ = z4, aNA = z4, aNB = z4;
        const int n = wv*16 + col;
#pragma unroll
        for (int c2 = 0; c2 < 2; ++c2) {
          const int cn = c2 ? 6 : 7;
          short8 bf[7];
#pragma unroll
          for (int i = 0; i < 7; ++i) if (i < cn) bf[i] = ld8(src, (c2*7 + i)*4 + quad, n);
#pragma unroll
          for (int i = 0; i < 7; ++i) if (i < cn) {
            int kt = c2*7 + i;
            aR  = MFMA16(wfa[kt],      bf[i], aR);
            aZ  = MFMA16(wfa[14 + kt], bf[i], aZ);
            aNB = MFMA16(wfa[28 + kt], bf[i], aNB);
            if (kt == 12) aNA = MFMA16(wfx, bf[i], aNA);
          }
        }
        short hq[4];
#pragma unroll
        for (int r = 0; r < 4; ++r) {
          float rg = sigm(aR[r] + bR[r]);
          float zg = sigm(aZ[r] + bZ[r]);
          float ng = tanhf(aNA[r] + bNi[r] + rg*(aNB[r] + bNh[r]));
          int m = quad*4 + r;
          float hpv = sm[G_HP + m*128 + n];
          float h = (1.f - zg)*ng + zg*hpv;
          sm[G_HP + m*128 + n] = h;
          hq[r] = rneb(h);
        }
        short4v hv = {hq[0], hq[1], hq[2], hq[3]};
        st4(dstW + (size_t)((hj*2 + (quad >> 1))*128 + n)*8 + (quad & 1)*4, hv);
        if (hj == 0) writeX(p, t + 1, tid);
      }
    } else if (role == 3) {                            // OUT, t = s-4
      const int t = s - 4;
      if (t >= 0 && t < TT) {
        const unsigned short* s3p = p.xb3 + (size_t)((t+1)&7) * S2;
        const unsigned short* s2p = p.xb2 + (size_t)((t+1)&7) * S2;
        const unsigned short* s1p = p.xb1 + (size_t)((t+1)&7) * S1;
        const unsigned short* wrs = p.wr + (size_t)(t&7) * SW;
        f32x4 a0[2] = {z4, z4}, a1[2] = {z4, z4};
#pragma unroll
        for (int nt = 0; nt < 2; ++nt) {
          const int n = npair*32 + nt*16 + col;
#pragma unroll
          for (int c2 = 0; c2 < 2; ++c2) {
            short8 bf[10];
#pragma unroll
            for (int i = 0; i < 10; ++i) {
              int o = (kh*20 + c2*10 + i)*4 + quad;
              short8 v;
              if      (o < 50)  v = relu8(ld8(s3p, o, n));
              else if (o < 100) v = relu8(ld8(s2p, o - 50, n));
              else if (o < 150) v = relu8(ld8(s1p, o - 100, n));
              else if (o < 158) v = ld8(wrs, o - 150, n);
              else { short8 zz = {0,0,0,0,0,0,0,0}; v = zz; }
              bf[i] = v;
            }
#pragma unroll
            for (int i = 0; i < 10; ++i) {
              int ktl = c2*10 + i;
              a0[nt] = MFMA16(wfa[ktl],      bf[i], a0[nt]);
              a1[nt] = MFMA16(wfa[20 + ktl], bf[i], a1[nt]);
            }
          }
        }
        float* P = sm + G_P;
        if (kh == 1) {
#pragma unroll
          for (int nt = 0; nt < 2; ++nt) {
            int cg = npair*32 + nt*16 + col;
            float* pc = P + cg*68 + quad*4;
            *(f32x4*)(pc)      = a0[nt];
            *(f32x4*)(pc + 16) = a1[nt];
          }
        }
        __syncthreads();
        if (kh == 0) {
#pragma unroll
          for (int nt = 0; nt < 2; ++nt) {
            int cg = npair*32 + nt*16 + col;
            const float* pc = P + cg*68 + quad*4;
            f32x4 p0 = *(const f32x4*)(pc);
            f32x4 p1 = *(const f32x4*)(pc + 16);
#pragma unroll
            for (int rt = 0; rt < 2; ++rt)
#pragma unroll
              for (int r = 0; r < 4; ++r) {
                int row = q*32 + rt*16 + quad*4 + r;
                float v = (rt ? a1[nt][r] + p1[r] : a0[nt][r] + p0[r]) + blr[rt*4 + r];
                if (row < 121) p.out[((size_t)cg*TT + t)*121 + row] = v;
              }
          }
        }
      }
    } else {                                           // ATTN, t = s-1
      const int t = s - 1;
      if (t >= 0 && t < TT) {
        const unsigned short* src = p.xb1 + (size_t)((t+1)&7) * S1;
        unsigned short* wdst = p.wr + (size_t)(t&7) * SW;
        f32x4 a0 = z4, a1 = z4;
        const int n = wv*16 + col;
#pragma unroll
        for (int c2 = 0; c2 < 2; ++c2) {
          const int cn = c2 ? 6 : 7;
          short8 bf[7];
#pragma unroll
          for (int i = 0; i < 7; ++i) if (i < cn) bf[i] = ld8(src, (c2*7 + i)*4 + quad, n);
#pragma unroll
          for (int i = 0; i < 7; ++i) if (i < cn) {
            int kt = c2*7 + i;
            a0 = MFMA16(wfa[kt],      bf[i], a0);
            a1 = MFMA16(wfa[13 + kt], bf[i], a1);
          }
        }
#pragma unroll
        for (int rt = 0; rt < 2; ++rt)
#pragma unroll
          for (int r = 0; r < 4; ++r) {
            int row = rt*16 + quad*4 + r;
            if (row < 30) sm[A_AL + row*132 + n] = (rt ? a1[r] : a0[r]);
          }
        __syncthreads();
        for (int idx = tid; idx < 30*128; idx += 512) {
          int l = idx >> 7, b = idx & 127;
          float v = expf(sm[A_AL + l*132 + b] + sm[A_BC + l]);
          if (l >= 20) { float kk = sm[A_KAP + (l-20)*128 + b] + v; sm[A_KAP + (l-20)*128 + b] = kk; v = kk; }
          sm[A_AL + l*132 + b] = v;
        }
        __syncthreads();
        for (int idx = tid; idx < 50*128; idx += 512) {
          int u = idx >> 7, b = idx & 127;
          float ph = 0.f;
#pragma unroll
          for (int j = 0; j < 10; ++j) {
            float al = sm[A_AL + j*132 + b];
            float be = sm[A_AL + (10 + j)*132 + b];
            float ka = sm[A_AL + (20 + j)*132 + b];
            float d = ka - (float)u;
            ph += al * expf(-be*d*d);
          }
          sm[A_PH + u*132 + b] = ph;
        }
        __syncthreads();
        for (int i = tid; i < 64*132; i += 512) sm[A_WR + i] = 0.f;
        __syncthreads();
        if (tid < 128) {
          int b = tid;
          const int* cidl = (const int*)(sm + A_CID);
          for (int u = 0; u < 50; ++u)
            sm[A_WR + cidl[b*50 + u]*132 + b] += sm[A_PH + u*132 + b];
        }
        __syncthreads();
        for (int idx = tid; idx < 8*128; idx += 512) {
          int o = idx >> 7, b = idx & 127;
          short8 v;
#pragma unroll
          for (int e = 0; e < 8; ++e) v[e] = rneb(sm[A_WR + (o*8 + e)*132 + b]);
          st8(wdst, o, b, v);
        }
      }
    }
    gbar(p.bar, 80u*(unsigned)(s + 2), tid);
  }
}

extern "C" void kernel_launch(void* const* d_in, const int* in_sizes, int n_in,
                              void* d_out, int out_size, void* d_ws, size_t ws_size,
                              hipStream_t stream)
{
  (void)in_sizes; (void)n_in; (void)out_size; (void)ws_size;
  Params p;
  p.seq = (const float*)d_in[0];
  p.cid = (const int*)  d_in[1];
  p.Wi1 = (const float*)d_in[2];  p.Wh1 = (const float*)d_in[3];
  p.bi1 = (const float*)d_in[4];  p.bh1 = (const float*)d_in[5];
  p.Wc  = (const float*)d_in[6];  p.bc  = (const float*)d_in[7];
  p.Wi2 = (const float*)d_in[8];  p.Wh2 = (const float*)d_in[9];
  p.bi2 = (const float*)d_in[10]; p.bh2 = (const float*)d_in[11];
  p.Wi3 = (const float*)d_in[12]; p.Wh3 = (const float*)d_in[13];
  p.bi3 = (const float*)d_in[14]; p.bh3 = (const float*)d_in[15];
  p.Wl  = (const float*)d_in[16]; p.bl  = (const float*)d_in[17];
  p.out = (float*)d_out;

  char* ws = (char*)d_ws;
  p.bar = (unsigned*)ws;                      ws += 256;
  p.xb1 = (unsigned short*)ws;                ws += (size_t)8 * S1 * 2;
  p.xb2 = (unsigned short*)ws;                ws += (size_t)8 * S2 * 2;
  p.xb3 = (unsigned short*)ws;                ws += (size_t)8 * S2 * 2;
  p.wr  = (unsigned short*)ws;                ws += (size_t)8 * SW * 2;

  hipMemsetAsync(d_ws, 0, 256, stream);       // zero barrier counter (ws is poisoned)

  hipFuncSetAttribute(reinterpret_cast<const void*>(hwnet_kernel),
                      hipFuncAttributeMaxDynamicSharedMemorySize, SMEMF * 4);

  void* args[] = { &p };
  hipLaunchCooperativeKernel(reinterpret_cast<void*>(hwnet_kernel),
                             dim3(80), dim3(512), args, SMEMF * 4, stream);
}

// Round 5
// 10912.415 us; speedup vs baseline: 5.2444x; 1.0174x over previous
//
#include <hip/hip_runtime.h>

#define TT 500
#define S1 (52*128*8)   // xb1 slot elems (416 k-rows = 52 octets)
#define S2 (50*128*8)   // xb2/xb3 slot elems (400 k-rows)
#define SW (8*128*8)    // wring slot elems (64 k-rows)

// dynamic LDS (floats)
#define G_P   0          // 128*68 partial-exchange           [GRU2/3, OUT]
#define G_HP  8704       // 16*128 persistent fp32 h-state    [GRU roles]
#define A_AL  0          // 30*132                            [ATTN]
#define A_PH  3960       // 50*132
#define A_WR  10560      // 64*132
#define A_KAP 19008      // 10*128 persistent kappa
#define A_CID 20288      // 128*50 ints
#define A_BC  26688      // 30
#define SMEMF 26720

// barrier region (in unsigned words): slot i at bar[i*16] (64 B apart),
// epoch at bar[1280] (own line). 8192 bytes total, memset to 0 pre-launch.
#define EPOCH_W 1280

typedef __attribute__((ext_vector_type(8))) short short8;
typedef __attribute__((ext_vector_type(4))) short short4v;
typedef __attribute__((ext_vector_type(4))) float f32x4;
typedef unsigned long long u64;

#define MFMA16(A,B,C) __builtin_amdgcn_mfma_f32_16x16x32_bf16((A),(B),(C),0,0,0)

struct Params {
  const float* seq; const int* cid;
  const float *Wi1,*Wh1,*bi1,*bh1;
  const float *Wc,*bc;
  const float *Wi2,*Wh2,*bi2,*bh2;
  const float *Wi3,*Wh3,*bi3,*bh3;
  const float *Wl,*bl;
  float* out;
  unsigned* bar;
  unsigned short *xb1, *xb2, *xb3, *wr;   // bf16 payload, swizzled [k>>3][n][k&7]
};

__device__ __forceinline__ short rneb(float f) {
  union { float f; unsigned u; } c; c.f = f;
  unsigned u = c.u;
  return (short)((u + 0x7FFFu + ((u >> 16) & 1u)) >> 16);
}
__device__ __forceinline__ float sigm(float x) { return 1.f / (1.f + expf(-x)); }

// Cross-WG payload: agent-scope relaxed atomics -> sc1-flagged loads/stores that
// bypass the (non-cross-XCD-coherent) L2 and hit the shared coherence point.
__device__ __forceinline__ short8 ld8(const unsigned short* b, int o, int n) {
  const u64* q = (const u64*)(b + (size_t)(o*128 + n)*8);
  union { u64 u[2]; short8 s; } c;
  c.u[0] = __hip_atomic_load(q,     __ATOMIC_RELAXED, __HIP_MEMORY_SCOPE_AGENT);
  c.u[1] = __hip_atomic_load(q + 1, __ATOMIC_RELAXED, __HIP_MEMORY_SCOPE_AGENT);
  return c.s;
}
__device__ __forceinline__ void st8(unsigned short* b, int o, int n, short8 v) {
  u64* q = (u64*)(b + (size_t)(o*128 + n)*8);
  union { short8 s; u64 u[2]; } c; c.s = v;
  __hip_atomic_store(q,     c.u[0], __ATOMIC_RELAXED, __HIP_MEMORY_SCOPE_AGENT);
  __hip_atomic_store(q + 1, c.u[1], __ATOMIC_RELAXED, __HIP_MEMORY_SCOPE_AGENT);
}
__device__ __forceinline__ void st4(unsigned short* addr, short4v v) {
  union { short4v s; u64 u; } c; c.s = v;
  __hip_atomic_store((u64*)addr, c.u, __ATOMIC_RELAXED, __HIP_MEMORY_SCOPE_AGENT);
}
__device__ __forceinline__ short8 relu8(short8 v) { short8 s = v >> 15; return v & ~s; }

// Worker side of the distributed barrier: per-wave vmcnt drain (release), then
// tid0 stores epoch k into this WG's OWN slot (no RMW, no line sharing), then
// spins read-only on the master-published epoch line.
__device__ __forceinline__ void wbar(unsigned* bar, int wg, unsigned k, int tid) {
  __builtin_amdgcn_s_waitcnt(0);
  __syncthreads();
  if (tid == 0) {
    __hip_atomic_store(bar + wg*16, k, __ATOMIC_RELAXED, __HIP_MEMORY_SCOPE_AGENT);
    while (__hip_atomic_load(bar + EPOCH_W, __ATOMIC_RELAXED, __HIP_MEMORY_SCOPE_AGENT) < k)
      __builtin_amdgcn_s_sleep(2);
  }
  __syncthreads();
}

__device__ __forceinline__ void writeX(const Params& p, int tn, int tid) {
  if (tn >= TT) return;
  unsigned short* dst = p.xb1 + (size_t)(tn & 7) * S1;
  if (tid < 128) {
    int n = tid;
    const float* s = p.seq + ((size_t)tn*128 + n)*3;
    short8 v = { rneb(s[0]), rneb(s[1]), rneb(s[2]), 0,0,0,0,0 };
    st8(dst, 50, n, v);
  } else if (tid < 256) {
    int n = tid - 128;
    short8 z = {0,0,0,0,0,0,0,0};
    st8(dst, 51, n, z);
  }
}

__global__ __launch_bounds__(512, 2) void hwnet_kernel(Params p)
{
  extern __shared__ float sm[];
  const int wg = blockIdx.x, tid = threadIdx.x;
  const int lane = tid & 63, wv = tid >> 6;
  const int quad = lane >> 4, col = lane & 15;

  // ---------------- master barrier WG ----------------
  if (wg == 80) {
    if (wv == 0) {
      for (unsigned k = 1; k <= (unsigned)(TT + 5); ++k) {
        for (;;) {
          unsigned a = __hip_atomic_load(p.bar + lane*16, __ATOMIC_RELAXED, __HIP_MEMORY_SCOPE_AGENT);
          unsigned b = (lane < 16)
            ? __hip_atomic_load(p.bar + (64 + lane)*16, __ATOMIC_RELAXED, __HIP_MEMORY_SCOPE_AGENT)
            : 0xFFFFFFFFu;
          unsigned v = a < b ? a : b;
#pragma unroll
          for (int off = 32; off; off >>= 1) {
            unsigned o = __shfl_xor(v, off, 64);
            v = v < o ? v : o;
          }
          if (v >= k) break;
        }
        __hip_atomic_store(p.bar + EPOCH_W, k, __ATOMIC_RELAXED, __HIP_MEMORY_SCOPE_AGENT);
      }
    }
    return;
  }

  int role, hj = 0, q = 0;
  if      (wg < 25) { role = 0; hj = wg; }        // GRU1
  else if (wg < 50) { role = 1; hj = wg - 25; }   // GRU2
  else if (wg < 75) { role = 2; hj = wg - 50; }   // GRU3
  else if (wg < 79) { role = 3; q  = wg - 75; }   // OUT
  else              { role = 4; }                  // ATTN

  const int kh = wv >> 2, npair = wv & 3;
  const f32x4 z4 = {0.f, 0.f, 0.f, 0.f};

  short8 wfa[42];
  short8 wfx = {0,0,0,0,0,0,0,0};

  // ---------------- one-time preload of weight fragments into registers ----------------
  if (role == 1 || role == 2) {
    const float* Wi = (role == 1) ? p.Wi2 : p.Wi3;
    const float* Wh = (role == 1) ? p.Wh2 : p.Wh3;
#pragma unroll
    for (int rt = 0; rt < 3; ++rt) {
      const int grow = rt*400 + hj*16 + col;
      const float* wi = Wi + (size_t)grow * 464;
      const float* wh = Wh + (size_t)grow * 400;
      if (kh == 0) {
#pragma unroll
        for (int ktl = 0; ktl < 14; ++ktl) {
          short8 f;
#pragma unroll
          for (int j = 0; j < 8; ++j) {
            int k = ktl*32 + quad*8 + j;                 // <448, all in Wi range
            f[j] = rneb(wi[k]);
          }
          wfa[rt*14 + ktl] = f;
        }
      } else {
#pragma unroll
        for (int ktl = 0; ktl < 13; ++ktl) {
          short8 f;
#pragma unroll
          for (int j = 0; j < 8; ++j) {
            int k = (14 + ktl)*32 + quad*8 + j;
            float v = (k < 464) ? wi[k] : wh[k - 464];
            if (rt == 2 && ktl == 0 && k < 464) v = 0.f; // n-gate: hi(B)-part only
            f[j] = rneb(v);
          }
          wfa[rt*14 + ktl] = f;
        }
      }
    }
    if (kh == 1) {  // n-gate lo(A)-part of boundary ktile 14
      const int grow = 2*400 + hj*16 + col;
      const float* wi = Wi + (size_t)grow * 464;
      short8 f;
#pragma unroll
      for (int j = 0; j < 8; ++j) {
        int k = 14*32 + quad*8 + j;
        f[j] = rneb((k < 464) ? wi[k] : 0.f);
      }
      wfx = f;
    }
  } else if (role == 0) {
#pragma unroll
    for (int rt = 0; rt < 3; ++rt) {
      const int grow = rt*400 + hj*16 + col;
      const float* whr = p.Wh1 + (size_t)grow * 400;
      const float* wir = p.Wi1 + (size_t)grow * 67;
#pragma unroll
      for (int ktl = 0; ktl < 13; ++ktl) {
        short8 f;
#pragma unroll
        for (int j = 0; j < 8; ++j) {
          int k = ktl*32 + quad*8 + j;
          float v = 0.f;
          if (k < 400) v = whr[k];
          else if (k < 403) v = wir[k - 400];
          if (rt == 2 && ktl == 12 && k >= 400) v = 0.f; // n-gate: lo(B)-part only
          f[j] = rneb(v);
        }
        wfa[rt*14 + ktl] = f;
      }
    }
    { // n-gate hi(A = x-cols) part of boundary ktile 12
      const int grow = 2*400 + hj*16 + col;
      const float* wir = p.Wi1 + (size_t)grow * 67;
      short8 f;
#pragma unroll
      for (int j = 0; j < 8; ++j) {
        int k = 12*32 + quad*8 + j;
        f[j] = rneb((k >= 400 && k < 403) ? wir[k - 400] : 0.f);
      }
      wfx = f;
    }
  } else if (role == 3) {
#pragma unroll
    for (int rt = 0; rt < 2; ++rt) {
      const int grow = q*32 + rt*16 + col;
      const float* wl = p.Wl + (size_t)grow * 1264;
#pragma unroll
      for (int ktl = 0; ktl < 20; ++ktl) {
        short8 f;
#pragma unroll
        for (int j = 0; j < 8; ++j) {
          int k = (kh*20 + ktl)*32 + quad*8 + j;
          f[j] = rneb((grow < 121 && k < 1264) ? wl[k] : 0.f);
        }
        wfa[rt*20 + ktl] = f;
      }
    }
  } else { // ATTN
#pragma unroll
    for (int rt = 0; rt < 2; ++rt) {
      const int grow = rt*16 + col;
      const float* wc = p.Wc + (size_t)grow * 400;
#pragma unroll
      for (int ktl = 0; ktl < 13; ++ktl) {
        short8 f;
#pragma unroll
        for (int j = 0; j < 8; ++j) {
          int k = ktl*32 + quad*8 + j;
          f[j] = rneb((grow < 30 && k < 400) ? wc[k] : 0.f);
        }
        wfa[rt*13 + ktl] = f;
      }
    }
    int* cidl = (int*)(sm + A_CID);
    for (int i = tid; i < 128*50; i += 512) cidl[i] = p.cid[i] & 63;
    for (int i = tid; i < 1280; i += 512) sm[A_KAP + i] = 0.f;
    for (int i = tid; i < 30; i += 512) sm[A_BC + i] = p.bc[i];
  }

  // biases into registers
  float bR[4], bZ[4], bNi[4], bNh[4], blr[8];
  if (role < 3) {
    const float* bi = role == 0 ? p.bi1 : role == 1 ? p.bi2 : p.bi3;
    const float* bh = role == 0 ? p.bh1 : role == 1 ? p.bh2 : p.bh3;
#pragma unroll
    for (int r = 0; r < 4; ++r) {
      int row = hj*16 + quad*4 + r;
      bR[r]  = bi[row] + bh[row];
      bZ[r]  = bi[400 + row] + bh[400 + row];
      bNi[r] = bi[800 + row];
      bNh[r] = bh[800 + row];
    }
    for (int i = tid; i < 2048; i += 512) sm[G_HP + i] = 0.f;
  }
  if (role == 3) {
#pragma unroll
    for (int rt = 0; rt < 2; ++rt)
#pragma unroll
      for (int r = 0; r < 4; ++r) {
        int row = q*32 + rt*16 + quad*4 + r;
        blr[rt*4 + r] = (row < 121) ? p.bl[row] : 0.f;
      }
  }

  // zero t=-1 ring content via sc1 stores (ws is poisoned every launch)
  if (role == 0) {
    u64* b0 = (u64*)(p.xb1 + (size_t)hj*2*128*8);
    for (int i = tid; i < 512; i += 512)
      __hip_atomic_store(b0 + i, 0ull, __ATOMIC_RELAXED, __HIP_MEMORY_SCOPE_AGENT);
    if (hj == 0) writeX(p, 0, tid);
  } else if (role == 1) {
    u64* b0 = (u64*)(p.xb2 + (size_t)hj*2*128*8);
    for (int i = tid; i < 512; i += 512)
      __hip_atomic_store(b0 + i, 0ull, __ATOMIC_RELAXED, __HIP_MEMORY_SCOPE_AGENT);
  } else if (role == 2) {
    u64* b0 = (u64*)(p.xb3 + (size_t)hj*2*128*8);
    for (int i = tid; i < 512; i += 512)
      __hip_atomic_store(b0 + i, 0ull, __ATOMIC_RELAXED, __HIP_MEMORY_SCOPE_AGENT);
  }

  wbar(p.bar, wg, 1u, tid);

  // ---------------- skewed pipeline main loop ----------------
  for (int s = 0; s < TT + 4; ++s) {
    if (role == 1 || role == 2) {                      // GRU2 (t=s-2) / GRU3 (t=s-3)
      const int t = s - (role == 1 ? 2 : 3);
      if (t >= 0 && t < TT) {
        const unsigned short* srcRelu = (role == 1 ? p.xb1 : p.xb2) + (size_t)((t+1)&7) * (role == 1 ? S1 : S2);
        const unsigned short* wrs     = p.wr + (size_t)(t&7) * SW;
        const unsigned short* srcOwn  = (role == 1 ? p.xb2 : p.xb3) + (size_t)(t&7) * S2;
        unsigned short*       dstW    = (role == 1 ? p.xb2 : p.xb3) + (size_t)((t+1)&7) * S2;
        f32x4 aR[2] = {z4, z4}, aZ[2] = {z4, z4}, aN[2] = {z4, z4}, aNB[2] = {z4, z4};
#pragma unroll
        for (int nt = 0; nt < 2; ++nt) {
          const int n = npair*32 + nt*16 + col;
          if (kh == 0) {
#pragma unroll
            for (int c2 = 0; c2 < 2; ++c2) {
              short8 bf[7];
#pragma unroll
              for (int i = 0; i < 7; ++i) {
                int o = (c2*7 + i)*4 + quad;
                bf[i] = (o < 50) ? relu8(ld8(srcRelu, o, n)) : ld8(wrs, o - 50, n);
              }
#pragma unroll
              for (int i = 0; i < 7; ++i) {
                int kt = c2*7 + i;
                aR[nt] = MFMA16(wfa[kt],      bf[i], aR[nt]);
                aZ[nt] = MFMA16(wfa[14 + kt], bf[i], aZ[nt]);
                aN[nt] = MFMA16(wfa[28 + kt], bf[i], aN[nt]);
              }
            }
          } else {
#pragma unroll
            for (int c2 = 0; c2 < 2; ++c2) {
              const int cn = c2 ? 6 : 7;
              short8 bf[7];
#pragma unroll
              for (int i = 0; i < 7; ++i) if (i < cn) {
                int o = (14 + c2*7 + i)*4 + quad;
                bf[i] = (o < 58) ? ld8(wrs, o - 50, n) : ld8(srcOwn, o - 58, n);
              }
#pragma unroll
              for (int i = 0; i < 7; ++i) if (i < cn) {
                int ktl = c2*7 + i;
                aR[nt]  = MFMA16(wfa[ktl],      bf[i], aR[nt]);
                aZ[nt]  = MFMA16(wfa[14 + ktl], bf[i], aZ[nt]);
                aNB[nt] = MFMA16(wfa[28 + ktl], bf[i], aNB[nt]);
                if (ktl == 0) aN[nt] = MFMA16(wfx, bf[i], aN[nt]);
              }
            }
          }
        }
        float* P = sm + G_P;
        if (kh == 1) {
#pragma unroll
          for (int nt = 0; nt < 2; ++nt) {
            int cg = npair*32 + nt*16 + col;
            float* pc = P + cg*68 + quad*4;
            *(f32x4*)(pc)      = aR[nt];
            *(f32x4*)(pc + 16) = aZ[nt];
            *(f32x4*)(pc + 32) = aN[nt];
            *(f32x4*)(pc + 48) = aNB[nt];
          }
        }
        __syncthreads();
        if (kh == 0) {
#pragma unroll
          for (int nt = 0; nt < 2; ++nt) {
            int cg = npair*32 + nt*16 + col;
            const float* pc = P + cg*68 + quad*4;
            f32x4 pR  = *(const f32x4*)(pc);
            f32x4 pZ  = *(const f32x4*)(pc + 16);
            f32x4 pNA = *(const f32x4*)(pc + 32);
            f32x4 pNB = *(const f32x4*)(pc + 48);
            short hq[4];
#pragma unroll
            for (int r = 0; r < 4; ++r) {
              float R  = aR[nt][r] + pR[r] + bR[r];
              float Z  = aZ[nt][r] + pZ[r] + bZ[r];
              float NA = aN[nt][r] + pNA[r] + bNi[r];
              float NB = pNB[r] + bNh[r];
              float rg = sigm(R), zg = sigm(Z);
              float ng = tanhf(NA + rg*NB);
              int m = quad*4 + r;
              float hpv = sm[G_HP + m*128 + cg];
              float h = (1.f - zg)*ng + zg*hpv;
              sm[G_HP + m*128 + cg] = h;
              hq[r] = rneb(h);
            }
            short4v hv = {hq[0], hq[1], hq[2], hq[3]};
            st4(dstW + (size_t)((hj*2 + (quad >> 1))*128 + cg)*8 + (quad & 1)*4, hv);
          }
        }
      }
    } else if (role == 0) {                            // GRU1, t = s
      const int t = s;
      if (t < TT) {
        const unsigned short* src = p.xb1 + (size_t)(t&7) * S1;
        unsigned short* dstW = p.xb1 + (size_t)((t+1)&7) * S1;
        f32x4 aR = z4, aZ = z4, aNA = z4, aNB = z4;
        const int n = wv*16 + col;
#pragma unroll
        for (int c2 = 0; c2 < 2; ++c2) {
          const int cn = c2 ? 6 : 7;
          short8 bf[7];
#pragma unroll
          for (int i = 0; i < 7; ++i) if (i < cn) bf[i] = ld8(src, (c2*7 + i)*4 + quad, n);
#pragma unroll
          for (int i = 0; i < 7; ++i) if (i < cn) {
            int kt = c2*7 + i;
            aR  = MFMA16(wfa[kt],      bf[i], aR);
            aZ  = MFMA16(wfa[14 + kt], bf[i], aZ);
            aNB = MFMA16(wfa[28 + kt], bf[i], aNB);
            if (kt == 12) aNA = MFMA16(wfx, bf[i], aNA);
          }
        }
        short hq[4];
#pragma unroll
        for (int r = 0; r < 4; ++r) {
          float rg = sigm(aR[r] + bR[r]);
          float zg = sigm(aZ[r] + bZ[r]);
          float ng = tanhf(aNA[r] + bNi[r] + rg*(aNB[r] + bNh[r]));
          int m = quad*4 + r;
          float hpv = sm[G_HP + m*128 + n];
          float h = (1.f - zg)*ng + zg*hpv;
          sm[G_HP + m*128 + n] = h;
          hq[r] = rneb(h);
        }
        short4v hv = {hq[0], hq[1], hq[2], hq[3]};
        st4(dstW + (size_t)((hj*2 + (quad >> 1))*128 + n)*8 + (quad & 1)*4, hv);
        if (hj == 0) writeX(p, t + 1, tid);
      }
    } else if (role == 3) {                            // OUT, t = s-4
      const int t = s - 4;
      if (t >= 0 && t < TT) {
        const unsigned short* s3p = p.xb3 + (size_t)((t+1)&7) * S2;
        const unsigned short* s2p = p.xb2 + (size_t)((t+1)&7) * S2;
        const unsigned short* s1p = p.xb1 + (size_t)((t+1)&7) * S1;
        const unsigned short* wrs = p.wr + (size_t)(t&7) * SW;
        f32x4 a0[2] = {z4, z4}, a1[2] = {z4, z4};
#pragma unroll
        for (int nt = 0; nt < 2; ++nt) {
          const int n = npair*32 + nt*16 + col;
#pragma unroll
          for (int c2 = 0; c2 < 2; ++c2) {
            short8 bf[10];
#pragma unroll
            for (int i = 0; i < 10; ++i) {
              int o = (kh*20 + c2*10 + i)*4 + quad;
              short8 v;
              if      (o < 50)  v = relu8(ld8(s3p, o, n));
              else if (o < 100) v = relu8(ld8(s2p, o - 50, n));
              else if (o < 150) v = relu8(ld8(s1p, o - 100, n));
              else if (o < 158) v = ld8(wrs, o - 150, n);
              else { short8 zz = {0,0,0,0,0,0,0,0}; v = zz; }
              bf[i] = v;
            }
#pragma unroll
            for (int i = 0; i < 10; ++i) {
              int ktl = c2*10 + i;
              a0[nt] = MFMA16(wfa[ktl],      bf[i], a0[nt]);
              a1[nt] = MFMA16(wfa[20 + ktl], bf[i], a1[nt]);
            }
          }
        }
        float* P = sm + G_P;
        if (kh == 1) {
#pragma unroll
          for (int nt = 0; nt < 2; ++nt) {
            int cg = npair*32 + nt*16 + col;
            float* pc = P + cg*68 + quad*4;
            *(f32x4*)(pc)      = a0[nt];
            *(f32x4*)(pc + 16) = a1[nt];
          }
        }
        __syncthreads();
        if (kh == 0) {
#pragma unroll
          for (int nt = 0; nt < 2; ++nt) {
            int cg = npair*32 + nt*16 + col;
            const float* pc = P + cg*68 + quad*4;
            f32x4 p0 = *(const f32x4*)(pc);
            f32x4 p1 = *(const f32x4*)(pc + 16);
#pragma unroll
            for (int rt = 0; rt < 2; ++rt)
#pragma unroll
              for (int r = 0; r < 4; ++r) {
                int row = q*32 + rt*16 + quad*4 + r;
                float v = (rt ? a1[nt][r] + p1[r] : a0[nt][r] + p0[r]) + blr[rt*4 + r];
                if (row < 121) p.out[((size_t)cg*TT + t)*121 + row] = v;
              }
          }
        }
      }
    } else {                                           // ATTN, t = s-1
      const int t = s - 1;
      if (t >= 0 && t < TT) {
        const unsigned short* src = p.xb1 + (size_t)((t+1)&7) * S1;
        unsigned short* wdst = p.wr + (size_t)(t&7) * SW;
        f32x4 a0 = z4, a1 = z4;
        const int n = wv*16 + col;
#pragma unroll
        for (int c2 = 0; c2 < 2; ++c2) {
          const int cn = c2 ? 6 : 7;
          short8 bf[7];
#pragma unroll
          for (int i = 0; i < 7; ++i) if (i < cn) bf[i] = ld8(src, (c2*7 + i)*4 + quad, n);
#pragma unroll
          for (int i = 0; i < 7; ++i) if (i < cn) {
            int kt = c2*7 + i;
            a0 = MFMA16(wfa[kt],      bf[i], a0);
            a1 = MFMA16(wfa[13 + kt], bf[i], a1);
          }
        }
#pragma unroll
        for (int rt = 0; rt < 2; ++rt)
#pragma unroll
          for (int r = 0; r < 4; ++r) {
            int row = rt*16 + quad*4 + r;
            if (row < 30) sm[A_AL + row*132 + n] = (rt ? a1[r] : a0[r]);
          }
        __syncthreads();
        for (int idx = tid; idx < 30*128; idx += 512) {
          int l = idx >> 7, b = idx & 127;
          float v = expf(sm[A_AL + l*132 + b] + sm[A_BC + l]);
          if (l >= 20) { float kk = sm[A_KAP + (l-20)*128 + b] + v; sm[A_KAP + (l-20)*128 + b] = kk; v = kk; }
          sm[A_AL + l*132 + b] = v;
        }
        __syncthreads();
        for (int idx = tid; idx < 50*128; idx += 512) {
          int u = idx >> 7, b = idx & 127;
          float ph = 0.f;
#pragma unroll
          for (int j = 0; j < 10; ++j) {
            float al = sm[A_AL + j*132 + b];
            float be = sm[A_AL + (10 + j)*132 + b];
            float ka = sm[A_AL + (20 + j)*132 + b];
            float d = ka - (float)u;
            ph += al * expf(-be*d*d);
          }
          sm[A_PH + u*132 + b] = ph;
        }
        __syncthreads();
        for (int i = tid; i < 64*132; i += 512) sm[A_WR + i] = 0.f;
        __syncthreads();
        if (tid < 128) {
          int b = tid;
          const int* cidl = (const int*)(sm + A_CID);
          for (int u = 0; u < 50; ++u)
            sm[A_WR + cidl[b*50 + u]*132 + b] += sm[A_PH + u*132 + b];
        }
        __syncthreads();
        for (int idx = tid; idx < 8*128; idx += 512) {
          int o = idx >> 7, b = idx & 127;
          short8 v;
#pragma unroll
          for (int e = 0; e < 8; ++e) v[e] = rneb(sm[A_WR + (o*8 + e)*132 + b]);
          st8(wdst, o, b, v);
        }
      }
    }
    wbar(p.bar, wg, (unsigned)(s + 2), tid);
  }
}

extern "C" void kernel_launch(void* const* d_in, const int* in_sizes, int n_in,
                              void* d_out, int out_size, void* d_ws, size_t ws_size,
                              hipStream_t stream)
{
  (void)in_sizes; (void)n_in; (void)out_size; (void)ws_size;
  Params p;
  p.seq = (const float*)d_in[0];
  p.cid = (const int*)  d_in[1];
  p.Wi1 = (const float*)d_in[2];  p.Wh1 = (const float*)d_in[3];
  p.bi1 = (const float*)d_in[4];  p.bh1 = (const float*)d_in[5];
  p.Wc  = (const float*)d_in[6];  p.bc  = (const float*)d_in[7];
  p.Wi2 = (const float*)d_in[8];  p.Wh2 = (const float*)d_in[9];
  p.bi2 = (const float*)d_in[10]; p.bh2 = (const float*)d_in[11];
  p.Wi3 = (const float*)d_in[12]; p.Wh3 = (const float*)d_in[13];
  p.bi3 = (const float*)d_in[14]; p.bh3 = (const float*)d_in[15];
  p.Wl  = (const float*)d_in[16]; p.bl  = (const float*)d_in[17];
  p.out = (float*)d_out;

  char* ws = (char*)d_ws;
  p.bar = (unsigned*)ws;                      ws += 8192;   // 80 slots * 64B + epoch line
  p.xb1 = (unsigned short*)ws;                ws += (size_t)8 * S1 * 2;
  p.xb2 = (unsigned short*)ws;                ws += (size_t)8 * S2 * 2;
  p.xb3 = (unsigned short*)ws;                ws += (size_t)8 * S2 * 2;
  p.wr  = (unsigned short*)ws;                ws += (size_t)8 * SW * 2;

  hipMemsetAsync(d_ws, 0, 8192, stream);      // zero barrier slots + epoch

  hipFuncSetAttribute(reinterpret_cast<const void*>(hwnet_kernel),
                      hipFuncAttributeMaxDynamicSharedMemorySize, SMEMF * 4);

  void* args[] = { &p };
  hipLaunchCooperativeKernel(reinterpret_cast<void*>(hwnet_kernel),
                             dim3(81), dim3(512), args, SMEMF * 4, stream);
}